// Round 1
// 6905.339 us; speedup vs baseline: 1.2344x; 1.2344x over previous
//
#include <hip/hip_runtime.h>

// Problem constants (fixed by setup_inputs)
#define B_   8
#define NQ_  200
#define S_   4096
#define E_   2048
#define H_   8
#define CH_  256     // E/H
#define NN_  100     // n (first-n queries -> gumbel branch)

typedef short v8s  __attribute__((ext_vector_type(8)));
typedef float v4f  __attribute__((ext_vector_type(4)));

// ---------------------------------------------------------------------------
// Threefry-2x32, JAX partitionable scheme: key = (0, 42); per flat index i:
// x = (hi32(i)=0, lo32(i)=i); bits = out0 ^ out1.
// ---------------------------------------------------------------------------
__device__ __forceinline__ unsigned rotl32(unsigned x, int d) {
    return (x << d) | (x >> (32 - d));
}

__device__ __forceinline__ unsigned threefry_bits(unsigned x0, unsigned x1) {
    const unsigned ks0 = 0u;
    const unsigned ks1 = 42u;
    const unsigned ks2 = 0x1BD11BDAu ^ 0u ^ 42u;
    x0 += ks0; x1 += ks1;
#define TFR(d) { x0 += x1; x1 = rotl32(x1, d); x1 ^= x0; }
    TFR(13) TFR(15) TFR(26) TFR(6)
    x0 += ks1; x1 += ks2 + 1u;
    TFR(17) TFR(29) TFR(16) TFR(24)
    x0 += ks2; x1 += ks0 + 2u;
    TFR(13) TFR(15) TFR(26) TFR(6)
    x0 += ks0; x1 += ks1 + 3u;
    TFR(17) TFR(29) TFR(16) TFR(24)
    x0 += ks1; x1 += ks2 + 4u;
    TFR(13) TFR(15) TFR(26) TFR(6)
    x0 += ks2; x1 += ks0 + 5u;
#undef TFR
    return x0 ^ x1;   // partitionable fold for 32-bit draws
}

// Exact replication of jax.random.uniform f32 bit manipulation, then Gumbel in f64.
__device__ __forceinline__ double gumbel_from_index(unsigned i) {
    unsigned bits = threefry_bits(0u, i);
    float f = __uint_as_float((bits >> 9) | 0x3F800000u) - 1.0f;   // [0,1)
    const float minv = 1e-6f;
    const float maxv = (float)(1.0 - 1e-6);
    float span = __fsub_rn(maxv, minv);
    float u = __fadd_rn(__fmul_rn(f, span), minv);   // mul then add, unfused like XLA
    u = fmaxf(minv, u);
    double lg = log((double)u);
    return -log(-lg);
}

// f32 -> bf16 (RNE)
__device__ __forceinline__ unsigned short f2bf(float f) {
    unsigned u = __float_as_uint(f);
    unsigned r = (u + 0x7FFFu + ((u >> 16) & 1u)) >> 16;
    return (unsigned short)r;
}

__device__ __forceinline__ float bf2f(unsigned short h) {
    return __uint_as_float(((unsigned)h) << 16);
}

// async global->LDS, 16B per lane
#define ASYNC16(g, l)                                                          \
    __builtin_amdgcn_global_load_lds(                                          \
        (const __attribute__((address_space(1))) unsigned*)(g),                \
        (__attribute__((address_space(3))) unsigned*)(l), 16, 0, 0)

// ---------------------------------------------------------------------------
// Generic tiled f32 GEMM: C = A * op(B) (+bias), 128x128 tile, 8x8 microtile.
// Microtile reads at stride-4 (2-way LDS aliasing = free).
// TB=false: B is KxN (ldb);  TB=true: B is NxK (ldb), i.e. C = A * B^T.
// Batched over blockIdx.z with z = zo*8 + zi offsets (pass 0 strides if unused).
// ---------------------------------------------------------------------------
template <bool TB, bool BIAS>
__global__ __launch_bounds__(256)
void gemm_f32(const float* __restrict__ A, const float* __restrict__ Bm,
              const float* __restrict__ bias, float* __restrict__ C,
              int M, int N, int K, int lda, int ldb, int ldc,
              long saO, long saI, long sbO, long sbI, long scO, long scI)
{
    const int z  = blockIdx.z;
    const int zo = z >> 3, zi = z & 7;
    A  += (long)zo * saO + (long)zi * saI;
    Bm += (long)zo * sbO + (long)zi * sbI;
    C  += (long)zo * scO + (long)zi * scI;

    const int tid = threadIdx.x;
    const int n0  = blockIdx.x * 128;
    const int m0  = blockIdx.y * 128;

    __shared__ float As[16][132];
    __shared__ float Bs[16][132];

    float acc[8][8] = {};

    const int tx = tid & 15, ty = tid >> 4;

    for (int k0 = 0; k0 < K; k0 += 16) {
        // ---- stage A tile (transposed): As[kk][m]
        {
            const int kk = (tid & 3) * 4;
#pragma unroll
            for (int p = 0; p < 2; ++p) {
                const int mi = (tid >> 2) + p * 64;
                const int m  = m0 + mi;
                float4 v = make_float4(0.f, 0.f, 0.f, 0.f);
                if (m < M) v = *(const float4*)(A + (long)m * lda + k0 + kk);
                As[kk + 0][mi] = v.x; As[kk + 1][mi] = v.y;
                As[kk + 2][mi] = v.z; As[kk + 3][mi] = v.w;
            }
        }
        // ---- stage B tile: Bs[kk][n]
        if (TB) {
            const int kk = (tid & 3) * 4;
#pragma unroll
            for (int p = 0; p < 2; ++p) {
                const int ni = (tid >> 2) + p * 64;
                const int nn = n0 + ni;
                float4 v = make_float4(0.f, 0.f, 0.f, 0.f);
                if (nn < N) v = *(const float4*)(Bm + (long)nn * ldb + k0 + kk);
                Bs[kk + 0][ni] = v.x; Bs[kk + 1][ni] = v.y;
                Bs[kk + 2][ni] = v.z; Bs[kk + 3][ni] = v.w;
            }
        } else {
#pragma unroll
            for (int p = 0; p < 2; ++p) {
                const int kk = (tid >> 5) + p * 8;
                const int ni = (tid & 31) * 4;
                float4 v = *(const float4*)(Bm + (long)(k0 + kk) * ldb + n0 + ni);
                *(float4*)&Bs[kk][ni] = v;
            }
        }
        __syncthreads();

#pragma unroll
        for (int kk = 0; kk < 16; ++kk) {
            float a[8], b[8];
            *(float4*)&a[0] = *(const float4*)&As[kk][ty * 4];
            *(float4*)&a[4] = *(const float4*)&As[kk][64 + ty * 4];
            *(float4*)&b[0] = *(const float4*)&Bs[kk][tx * 4];
            *(float4*)&b[4] = *(const float4*)&Bs[kk][64 + tx * 4];
#pragma unroll
            for (int i = 0; i < 8; ++i)
#pragma unroll
                for (int j = 0; j < 8; ++j)
                    acc[i][j] += a[i] * b[j];
        }
        __syncthreads();
    }

    // ---- epilogue (rows: i<4 -> m0+ty*4+i, i>=4 -> m0+64+ty*4+i-4;
    //                cols: j<4 -> n0+tx*4+j, j>=4 -> n0+64+tx*4+j-4)
    float bj[8] = {};
    if (BIAS) {
#pragma unroll
        for (int j = 0; j < 4; ++j) bj[j]     = bias[n0 + tx * 4 + j];
#pragma unroll
        for (int j = 0; j < 4; ++j) bj[4 + j] = bias[n0 + 64 + tx * 4 + j];
    }
#pragma unroll
    for (int i = 0; i < 8; ++i) {
        const int m = m0 + (i < 4 ? ty * 4 + i : 64 + ty * 4 + (i - 4));
        if (m >= M) continue;
        float4 o0, o1;
        o0.x = acc[i][0] + bj[0]; o0.y = acc[i][1] + bj[1];
        o0.z = acc[i][2] + bj[2]; o0.w = acc[i][3] + bj[3];
        o1.x = acc[i][4] + bj[4]; o1.y = acc[i][5] + bj[5];
        o1.z = acc[i][6] + bj[6]; o1.w = acc[i][7] + bj[7];
        float* cp = C + (long)m * ldc + n0;
        *(float4*)(cp + tx * 4)      = o0;
        *(float4*)(cp + 64 + tx * 4) = o1;
    }
}

// ---------------------------------------------------------------------------
// bf16 MFMA GEMM (m97 structure): C(f32, MxN) = A(bf16, MxK) * Bt(bf16, NxK)^T
// 128x128 tile, BK=32, 4 waves, 4x4 16x16x32 MFMA tiles per wave.
// ACC=true: C += result (stream-ordered accumulation across passes, used by
// the bf16x3 split-precision kp projection).
// ---------------------------------------------------------------------------
template <bool BIAS, bool ACC>
__global__ __launch_bounds__(256)
void gemm_bf16_bt(const unsigned short* __restrict__ A,
                  const unsigned short* __restrict__ Bt,
                  const float* __restrict__ bias,
                  float* __restrict__ C,
                  int M, int N, int K)
{
    __shared__ unsigned short Asm[128 * 32];
    __shared__ unsigned short Bsm[128 * 32];

    const int tid  = threadIdx.x;
    const int lane = tid & 63;
    const int wave = tid >> 6;
    const int m0 = blockIdx.y * 128;
    const int n0 = blockIdx.x * 128;

    const int woffm = (wave & 1) * 64;
    const int woffn = (wave >> 1) * 64;
    const int mrow = lane & 15;
    const int quad = lane >> 4;
    const int ko   = quad * 8;          // k-offset of this lane's fragment

    v4f acc[4][4] = {};

    // staging addresses: chunk c (0..511): row = c>>2, k-elt-offset = (c&3)*8
    const long  arow0 = (long)(m0 + (tid >> 2)) * K + (tid & 3) * 8;
    const long  arow1 = (long)(m0 + 64 + (tid >> 2)) * K + (tid & 3) * 8;
    const long  brow0 = (long)(n0 + (tid >> 2)) * K + (tid & 3) * 8;
    const long  brow1 = (long)(n0 + 64 + (tid >> 2)) * K + (tid & 3) * 8;

    for (int k0 = 0; k0 < K; k0 += 32) {
        ASYNC16(A + arow0 + k0,  &Asm[tid * 8]);
        ASYNC16(A + arow1 + k0,  &Asm[(256 + tid) * 8]);
        ASYNC16(Bt + brow0 + k0, &Bsm[tid * 8]);
        ASYNC16(Bt + brow1 + k0, &Bsm[(256 + tid) * 8]);
        __syncthreads();

        v8s a[4], b[4];
#pragma unroll
        for (int i = 0; i < 4; ++i)
            a[i] = *(const v8s*)&Asm[(woffm + i * 16 + mrow) * 32 + ko];
#pragma unroll
        for (int j = 0; j < 4; ++j)
            b[j] = *(const v8s*)&Bsm[(woffn + j * 16 + mrow) * 32 + ko];
#pragma unroll
        for (int i = 0; i < 4; ++i)
#pragma unroll
            for (int j = 0; j < 4; ++j)
                acc[i][j] = __builtin_amdgcn_mfma_f32_16x16x32_bf16(
                    a[i], b[j], acc[i][j], 0, 0, 0);
        __syncthreads();
    }

    // epilogue: D col = lane&15, row = quad*4 + r
    const int col = mrow;
    const int r0  = quad * 4;
#pragma unroll
    for (int j = 0; j < 4; ++j) {
        const int n = n0 + woffn + j * 16 + col;
        const float bv = BIAS ? bias[n] : 0.f;
#pragma unroll
        for (int i = 0; i < 4; ++i) {
            const int mbase = m0 + woffm + i * 16 + r0;
#pragma unroll
            for (int r = 0; r < 4; ++r) {
                const int m = mbase + r;
                if (m < M) {
                    float o = acc[i][j][r] + bv;
                    if (ACC) o += C[(long)m * N + n];
                    C[(long)m * N + n] = o;
                }
            }
        }
    }
}

// ---------------------------------------------------------------------------
// Casts
// ---------------------------------------------------------------------------
__global__ __launch_bounds__(256)
void cast_f32_bf16(const float* __restrict__ in, unsigned short* __restrict__ out, long n)
{
    long i = ((long)blockIdx.x * 256 + threadIdx.x) * 8;
    if (i + 8 <= n) {
        float4 v0 = *(const float4*)(in + i);
        float4 v1 = *(const float4*)(in + i + 4);
        ushort4 a, b;
        a.x = f2bf(v0.x); a.y = f2bf(v0.y); a.z = f2bf(v0.z); a.w = f2bf(v0.w);
        b.x = f2bf(v1.x); b.y = f2bf(v1.y); b.z = f2bf(v1.z); b.w = f2bf(v1.w);
        *(ushort4*)(out + i)     = a;
        *(ushort4*)(out + i + 4) = b;
    } else {
        for (; i < n; ++i) out[i] = f2bf(in[i]);
    }
}

// f32 -> (hi bf16, lo bf16) with x ~= hi + lo; lo = bf16(x - f32(hi)).
// Residual after hi+lo is ~2^-17 relative: split-precision GEMM inputs.
__global__ __launch_bounds__(256)
void split_cast_hi_lo(const float* __restrict__ in,
                      unsigned short* __restrict__ hi,
                      unsigned short* __restrict__ lo, long n)
{
    long i = ((long)blockIdx.x * 256 + threadIdx.x) * 8;
    if (i + 8 <= n) {
        float4 v0 = *(const float4*)(in + i);
        float4 v1 = *(const float4*)(in + i + 4);
        float x[8] = {v0.x, v0.y, v0.z, v0.w, v1.x, v1.y, v1.z, v1.w};
        unsigned short h[8], l[8];
#pragma unroll
        for (int j = 0; j < 8; ++j) {
            unsigned short hb = f2bf(x[j]);
            h[j] = hb;
            l[j] = f2bf(x[j] - bf2f(hb));
        }
        *(ushort4*)(hi + i)     = make_ushort4(h[0], h[1], h[2], h[3]);
        *(ushort4*)(hi + i + 4) = make_ushort4(h[4], h[5], h[6], h[7]);
        *(ushort4*)(lo + i)     = make_ushort4(l[0], l[1], l[2], l[3]);
        *(ushort4*)(lo + i + 4) = make_ushort4(l[4], l[5], l[6], l[7]);
    } else {
        for (; i < n; ++i) {
            unsigned short hb = f2bf(in[i]);
            hi[i] = hb;
            lo[i] = f2bf(in[i] - bf2f(hb));
        }
    }
}

// W (Kd x Nd f32, row-major) -> Wt (Nd x Kd bf16, row-major)
__global__ __launch_bounds__(256)
void transpose_cast(const float* __restrict__ W, unsigned short* __restrict__ Wt,
                    int Kd, int Nd)
{
    __shared__ float t[32][33];
    const int nb = blockIdx.x * 32, kb = blockIdx.y * 32;
    const int tx = threadIdx.x & 31, ty = threadIdx.x >> 5;
#pragma unroll
    for (int p = 0; p < 4; ++p)
        t[ty + p * 8][tx] = W[(long)(kb + ty + p * 8) * Nd + nb + tx];
    __syncthreads();
#pragma unroll
    for (int p = 0; p < 4; ++p)
        Wt[(long)(nb + ty + p * 8) * Kd + kb + tx] = f2bf(t[tx][ty + p * 8]);
}

// W (Kd x Nd f32) -> WtHi, WtLo (Nd x Kd bf16 each), hi/lo split as above.
__global__ __launch_bounds__(256)
void transpose_split_cast(const float* __restrict__ W,
                          unsigned short* __restrict__ WtHi,
                          unsigned short* __restrict__ WtLo,
                          int Kd, int Nd)
{
    __shared__ float t[32][33];
    const int nb = blockIdx.x * 32, kb = blockIdx.y * 32;
    const int tx = threadIdx.x & 31, ty = threadIdx.x >> 5;
#pragma unroll
    for (int p = 0; p < 4; ++p)
        t[ty + p * 8][tx] = W[(long)(kb + ty + p * 8) * Nd + nb + tx];
    __syncthreads();
#pragma unroll
    for (int p = 0; p < 4; ++p) {
        float x = t[tx][ty + p * 8];
        unsigned short hb = f2bf(x);
        long idx = (long)(nb + ty + p * 8) * Kd + kb + tx;
        WtHi[idx] = hb;
        WtLo[idx] = f2bf(x - bf2f(hb));
    }
}

// ---------------------------------------------------------------------------
// Row 1/||row|| (double) over E_ elements.
// ---------------------------------------------------------------------------
__global__ __launch_bounds__(256)
void row_invnorm(const float* __restrict__ src, double* __restrict__ out,
                 int perBatch, long batchStride)
{
    const int r = blockIdx.x;
    const int b = r / perBatch, i = r % perBatch;
    const float* row = src + (long)b * batchStride + (long)i * E_;
    double s = 0.0;
    for (int c = threadIdx.x; c < E_; c += 256) {
        float v = row[c];
        s += (double)v * (double)v;
    }
    for (int off = 32; off; off >>= 1) s += __shfl_down(s, off, 64);
    __shared__ double wred[4];
    if ((threadIdx.x & 63) == 0) wred[threadIdx.x >> 6] = s;
    __syncthreads();
    if (threadIdx.x == 0)
        out[r] = 1.0 / sqrt(wred[0] + wred[1] + wred[2] + wred[3]);
}

// ---------------------------------------------------------------------------
// Gumbel branch: for each (b,h,k) compute argmax_q [ (cos(q1h_q,k1h_k)+g)/tau ]
// and scatter-add vh[k] into outcat row idx (atomic f32).
// ---------------------------------------------------------------------------
__global__ __launch_bounds__(256)
void gumbel_argmax_scatter(const float* __restrict__ qp, const float* __restrict__ kp,
                           const float* __restrict__ vp,
                           const double* __restrict__ invqn, const double* __restrict__ invkn,
                           const float* __restrict__ taup,
                           float* __restrict__ outcat)
{
    const int kt  = blockIdx.x;            // 0..127
    const int h   = blockIdx.y;
    const int b   = blockIdx.z;
    const int tid = threadIdx.x;
    const int k0  = kt * 32;

    __shared__ double gl[NN_ * 32];        // 25.6 KB
    __shared__ int    idxs[32];

    const double tau = (double)taup[0];

    for (int e = tid; e < NN_ * 32; e += 256) {
        const int q = e >> 5, kl = e & 31;
        const unsigned i = (unsigned)(((b * H_ + h) * NN_ + q) * S_ + (k0 + kl));
        gl[e] = gumbel_from_index(i);
    }
    __syncthreads();

    const int kl = tid >> 3, l8 = tid & 7;

    float ks[32];
    const float* krow = kp + ((long)b * S_ + (k0 + kl)) * E_ + h * CH_ + l8 * 32;
#pragma unroll
    for (int j4 = 0; j4 < 8; ++j4)
        *(float4*)&ks[j4 * 4] = *(const float4*)(krow + j4 * 4);

    const double ikn = invkn[b * S_ + k0 + kl];
    double best = -1e300;
    int bi = 0;

    for (int q = 0; q < NN_; ++q) {
        const float* qrow = qp + ((long)b * NQ_ + q) * E_ + h * CH_ + l8 * 32;
        float s = 0.f;
#pragma unroll
        for (int j4 = 0; j4 < 8; ++j4) {
            float4 v = *(const float4*)(qrow + j4 * 4);
            s += ks[j4 * 4 + 0] * v.x + ks[j4 * 4 + 1] * v.y +
                 ks[j4 * 4 + 2] * v.z + ks[j4 * 4 + 3] * v.w;
        }
        s += __shfl_xor(s, 1, 64);
        s += __shfl_xor(s, 2, 64);
        s += __shfl_xor(s, 4, 64);
        if (l8 == 0) {
            double zv = ((double)s * invqn[b * NN_ + q] * ikn + gl[q * 32 + kl]) / tau;
            if (zv > best) { best = zv; bi = q; }
        }
    }
    if (l8 == 0) idxs[kl] = bi;
    __syncthreads();

    for (int kk = 0; kk < 32; ++kk) {
        const int row = idxs[kk];
        const float v = vp[((long)b * S_ + (k0 + kk)) * E_ + h * CH_ + tid];
        atomicAdd(outcat + ((long)b * NQ_ + row) * E_ + h * CH_ + tid, v);
    }
}

// ---------------------------------------------------------------------------
// Row softmax with 1/16 scale folded in.
// ---------------------------------------------------------------------------
__global__ __launch_bounds__(256)
void softmax_rows(float* __restrict__ S2)
{
    const long r = blockIdx.x;
    float* row = S2 + r * (long)S_;
    __shared__ float buf[S_];
    __shared__ float wred[4];
    __shared__ float wsum[4];
    const int tid = threadIdx.x;

    float mx = -1e30f;
    for (int c = tid; c < S_; c += 256) {
        float v = row[c];
        buf[c] = v;
        mx = fmaxf(mx, v);
    }
    for (int off = 32; off; off >>= 1) mx = fmaxf(mx, __shfl_xor(mx, off, 64));
    if ((tid & 63) == 0) wred[tid >> 6] = mx;
    __syncthreads();
    mx = fmaxf(fmaxf(wred[0], wred[1]), fmaxf(wred[2], wred[3]));

    float sum = 0.f;
    for (int c = tid; c < S_; c += 256) {
        float p = __expf((buf[c] - mx) * 0.0625f);
        buf[c] = p;
        sum += p;
    }
    for (int off = 32; off; off >>= 1) sum += __shfl_xor(sum, off, 64);
    if ((tid & 63) == 0) wsum[tid >> 6] = sum;
    __syncthreads();
    sum = wsum[0] + wsum[1] + wsum[2] + wsum[3];
    const float inv = 1.0f / sum;
    for (int c = tid; c < S_; c += 256) row[c] = buf[c] * inv;
}

// ---------------------------------------------------------------------------
// Host-side orchestration.
// Workspace layout (total 668,211,456 B, exactly packed):
//   [0            , 13,107,200 )  qp  f32 1600x2048
//   [13,107,200   , 281,542,656)  kp  f32 32768x2048
//   [281,542,656  , 549,978,112)  vp  f32 32768x2048        (BEFORE vp GEMM:)
//     [281,542,656, 415,760,384)    k_hi bf16 32768x2048  (kp-phase scratch)
//     [415,760,384, 549,978,112)    k_lo bf16 32768x2048  (kp-phase scratch)
//   [549,978,112  , 563,085,312)  outcat f32 1600x2048
//   [563,085,312  , 667,942,912)  S2  f32 64x100x4096       (time-shared:)
//     [563,085,312, 571,473,920)    wk_hi^T bf16 (kp phase only)
//     [571,473,920, 579,862,528)    wk_lo^T bf16 (kp phase only)
//     [563,085,312, 630,194,176)    v_bf16 chunk 16384x2048 (vp phase only)
//     [630,194,176, 638,582,784)    wT1 = wv^T bf16         (vp phase only)
//     [563,085,312, 569,901,056)    out_bf16 1664x2048 (after S2 consumed)
//     [569,901,056, 578,289,664)    wT2 = wo^T bf16   (after S2 consumed)
//   [667,942,912  , 667,949,312)  iqn  800 f64
//   [667,949,312  , 668,211,456)  ikn  32768 f64
// ---------------------------------------------------------------------------
extern "C" void kernel_launch(void* const* d_in, const int* in_sizes, int n_in,
                              void* d_out, int out_size, void* d_ws, size_t ws_size,
                              hipStream_t stream)
{
    const float* q   = (const float*)d_in[0];
    const float* k   = (const float*)d_in[1];
    const float* v   = (const float*)d_in[2];
    const float* wq  = (const float*)d_in[3];
    const float* bq  = (const float*)d_in[4];
    const float* wk  = (const float*)d_in[5];
    const float* bk  = (const float*)d_in[6];
    const float* wv  = (const float*)d_in[7];
    const float* bv  = (const float*)d_in[8];
    const float* wo  = (const float*)d_in[9];
    const float* bo  = (const float*)d_in[10];
    const float* tau = (const float*)d_in[11];

    char* ws = (char*)d_ws;
    float*          qp       = (float*)(ws + 0L);
    float*          kp       = (float*)(ws + 13107200L);
    float*          vp       = (float*)(ws + 281542656L);
    unsigned short* k_hi     = (unsigned short*)(ws + 281542656L);   // vp region
    unsigned short* k_lo     = (unsigned short*)(ws + 415760384L);   // vp region
    float*          outcat   = (float*)(ws + 549978112L);
    float*          S2       = (float*)(ws + 563085312L);
    unsigned short* wkThi    = (unsigned short*)(ws + 563085312L);   // S2 region
    unsigned short* wkTlo    = (unsigned short*)(ws + 571473920L);   // S2 region
    unsigned short* v_bf16c  = (unsigned short*)(ws + 563085312L);   // S2 region
    unsigned short* wT1      = (unsigned short*)(ws + 630194176L);   // S2 region
    unsigned short* out_bf16 = (unsigned short*)(ws + 563085312L);
    unsigned short* wT2      = (unsigned short*)(ws + 569901056L);
    double*         iqn      = (double*)(ws + 667942912L);
    double*         ikn      = (double*)(ws + 667949312L);

    const dim3 blk(256);

    // Phase A: kp = k @ wk + bk via bf16x3 split-precision MFMA.
    // hi*hi + hi*lo + lo*hi; residual ~2^-17 rel per term cancels over the
    // 2048-dot to ~2e-7 on cosine scores — below f32 accumulation-order noise,
    // so gumbel-argmax decisions are preserved.
    transpose_split_cast<<<dim3(64, 64), blk, 0, stream>>>(wk, wkThi, wkTlo, 2048, 2048);
    split_cast_hi_lo<<<dim3(32768), blk, 0, stream>>>(k, k_hi, k_lo, (long)32768 * 2048);
    gemm_bf16_bt<true, false><<<dim3(16, 256), blk, 0, stream>>>(
        k_hi, wkThi, bk, kp, 32768, 2048, 2048);
    gemm_bf16_bt<false, true><<<dim3(16, 256), blk, 0, stream>>>(
        k_hi, wkTlo, nullptr, kp, 32768, 2048, 2048);
    gemm_bf16_bt<false, true><<<dim3(16, 256), blk, 0, stream>>>(
        k_lo, wkThi, nullptr, kp, 32768, 2048, 2048);

    // Phase B: qp in f32 (argmax q-side precision; only 1600 rows, cheap).
    gemm_f32<false, true><<<dim3(16, 13, 1), blk, 0, stream>>>(
        q, wq, bq, qp, 1600, 2048, 2048, 2048, 2048, 2048, 0, 0, 0, 0, 0, 0);

    // Phase A2: vp via bf16 MFMA, two M-chunks (scratch fits in S2 region,
    // which frees the vp region that k_hi/k_lo occupied).
    transpose_cast<<<dim3(64, 64), blk, 0, stream>>>(wv, wT1, 2048, 2048);
    for (int c = 0; c < 2; ++c) {
        cast_f32_bf16<<<dim3(16384), blk, 0, stream>>>(
            v + (long)c * 16384 * 2048, v_bf16c, (long)16384 * 2048);
        gemm_bf16_bt<true, false><<<dim3(16, 128), blk, 0, stream>>>(
            v_bf16c, wT1, bv, vp + (long)c * 16384 * 2048, 16384, 2048, 2048);
    }

    // Phase C: row norms + gumbel scatter (out1 rows 0..99 of outcat)
    row_invnorm<<<dim3(800), blk, 0, stream>>>(qp, iqn, NN_, (long)NQ_ * E_);
    row_invnorm<<<dim3(32768), blk, 0, stream>>>(kp, ikn, S_, (long)S_ * E_);
    hipMemsetAsync(outcat, 0, 13107200, stream);
    gumbel_argmax_scatter<<<dim3(128, 8, 8), blk, 0, stream>>>(
        qp, kp, vp, iqn, ikn, tau, outcat);

    // Phase D: attn2 -> outcat rows 100..199
    gemm_f32<true, false><<<dim3(32, 1, 64), blk, 0, stream>>>(
        qp + (long)NN_ * E_, kp, nullptr, S2,
        100, 4096, 256, 2048, 2048, 4096,
        (long)NQ_ * E_, (long)CH_,
        (long)S_ * E_, (long)CH_,
        (long)H_ * NN_ * S_, (long)NN_ * S_);
    softmax_rows<<<dim3(6400), blk, 0, stream>>>(S2);
    gemm_f32<false, false><<<dim3(2, 1, 64), blk, 0, stream>>>(
        S2, vp, nullptr, outcat + (long)NN_ * E_,
        100, 256, 4096, 4096, 2048, 2048,
        (long)H_ * NN_ * S_, (long)NN_ * S_,
        (long)S_ * E_, (long)CH_,
        (long)NQ_ * E_, (long)CH_);

    // Phase E: final projection via bf16 MFMA (S2 region reused for scratch)
    cast_f32_bf16<<<dim3(1600), blk, 0, stream>>>(outcat, out_bf16, (long)1600 * 2048);
    transpose_cast<<<dim3(64, 64), blk, 0, stream>>>(wo, wT2, 2048, 2048);
    gemm_bf16_bt<true, false><<<dim3(16, 13), blk, 0, stream>>>(
        out_bf16, wT2, bo, (float*)d_out, 1600, 2048, 2048);
}

// Round 2
// 3849.083 us; speedup vs baseline: 2.2145x; 1.7940x over previous
//
#include <hip/hip_runtime.h>

// Problem constants (fixed by setup_inputs)
#define B_   8
#define NQ_  200
#define S_   4096
#define E_   2048
#define H_   8
#define CH_  256     // E/H
#define NN_  100     // n (first-n queries -> gumbel branch)

typedef short v8s  __attribute__((ext_vector_type(8)));
typedef float v4f  __attribute__((ext_vector_type(4)));

// ---------------------------------------------------------------------------
// Threefry-2x32, JAX partitionable scheme: key = (0, 42); per flat index i:
// x = (hi32(i)=0, lo32(i)=i); bits = out0 ^ out1.
// ---------------------------------------------------------------------------
__device__ __forceinline__ unsigned rotl32(unsigned x, int d) {
    return (x << d) | (x >> (32 - d));
}

__device__ __forceinline__ unsigned threefry_bits(unsigned x0, unsigned x1) {
    const unsigned ks0 = 0u;
    const unsigned ks1 = 42u;
    const unsigned ks2 = 0x1BD11BDAu ^ 0u ^ 42u;
    x0 += ks0; x1 += ks1;
#define TFR(d) { x0 += x1; x1 = rotl32(x1, d); x1 ^= x0; }
    TFR(13) TFR(15) TFR(26) TFR(6)
    x0 += ks1; x1 += ks2 + 1u;
    TFR(17) TFR(29) TFR(16) TFR(24)
    x0 += ks2; x1 += ks0 + 2u;
    TFR(13) TFR(15) TFR(26) TFR(6)
    x0 += ks0; x1 += ks1 + 3u;
    TFR(17) TFR(29) TFR(16) TFR(24)
    x0 += ks1; x1 += ks2 + 4u;
    TFR(13) TFR(15) TFR(26) TFR(6)
    x0 += ks2; x1 += ks0 + 5u;
#undef TFR
    return x0 ^ x1;   // partitionable fold for 32-bit draws
}

// Exact replication of jax.random.uniform f32 bit manipulation, then Gumbel in f64.
__device__ __forceinline__ double gumbel_from_index(unsigned i) {
    unsigned bits = threefry_bits(0u, i);
    float f = __uint_as_float((bits >> 9) | 0x3F800000u) - 1.0f;   // [0,1)
    const float minv = 1e-6f;
    const float maxv = (float)(1.0 - 1e-6);
    float span = __fsub_rn(maxv, minv);
    float u = __fadd_rn(__fmul_rn(f, span), minv);   // mul then add, unfused like XLA
    u = fmaxf(minv, u);
    double lg = log((double)u);
    return -log(-lg);
}

// f32 -> bf16 (RNE)
__device__ __forceinline__ unsigned short f2bf(float f) {
    unsigned u = __float_as_uint(f);
    unsigned r = (u + 0x7FFFu + ((u >> 16) & 1u)) >> 16;
    return (unsigned short)r;
}

__device__ __forceinline__ float bf2f(unsigned short h) {
    return __uint_as_float(((unsigned)h) << 16);
}

// async global->LDS, 16B per lane
#define ASYNC16(g, l)                                                          \
    __builtin_amdgcn_global_load_lds(                                          \
        (const __attribute__((address_space(1))) unsigned*)(g),                \
        (__attribute__((address_space(3))) unsigned*)(l), 16, 0, 0)

// ---------------------------------------------------------------------------
// Generic tiled f32 GEMM: C = A * op(B) (+bias), 128x128 tile, 8x8 microtile.
// TB=false: B is KxN (ldb);  TB=true: B is NxK (ldb), i.e. C = A * B^T.
// Batched over blockIdx.z with z = zo*8 + zi offsets (pass 0 strides if unused).
// ---------------------------------------------------------------------------
template <bool TB, bool BIAS>
__global__ __launch_bounds__(256)
void gemm_f32(const float* __restrict__ A, const float* __restrict__ Bm,
              const float* __restrict__ bias, float* __restrict__ C,
              int M, int N, int K, int lda, int ldb, int ldc,
              long saO, long saI, long sbO, long sbI, long scO, long scI)
{
    const int z  = blockIdx.z;
    const int zo = z >> 3, zi = z & 7;
    A  += (long)zo * saO + (long)zi * saI;
    Bm += (long)zo * sbO + (long)zi * sbI;
    C  += (long)zo * scO + (long)zi * scI;

    const int tid = threadIdx.x;
    const int n0  = blockIdx.x * 128;
    const int m0  = blockIdx.y * 128;

    __shared__ float As[16][132];
    __shared__ float Bs[16][132];

    float acc[8][8] = {};

    const int tx = tid & 15, ty = tid >> 4;

    for (int k0 = 0; k0 < K; k0 += 16) {
        // ---- stage A tile (transposed): As[kk][m]
        {
            const int kk = (tid & 3) * 4;
#pragma unroll
            for (int p = 0; p < 2; ++p) {
                const int mi = (tid >> 2) + p * 64;
                const int m  = m0 + mi;
                float4 v = make_float4(0.f, 0.f, 0.f, 0.f);
                if (m < M) v = *(const float4*)(A + (long)m * lda + k0 + kk);
                As[kk + 0][mi] = v.x; As[kk + 1][mi] = v.y;
                As[kk + 2][mi] = v.z; As[kk + 3][mi] = v.w;
            }
        }
        // ---- stage B tile: Bs[kk][n]
        if (TB) {
            const int kk = (tid & 3) * 4;
#pragma unroll
            for (int p = 0; p < 2; ++p) {
                const int ni = (tid >> 2) + p * 64;
                const int nn = n0 + ni;
                float4 v = make_float4(0.f, 0.f, 0.f, 0.f);
                if (nn < N) v = *(const float4*)(Bm + (long)nn * ldb + k0 + kk);
                Bs[kk + 0][ni] = v.x; Bs[kk + 1][ni] = v.y;
                Bs[kk + 2][ni] = v.z; Bs[kk + 3][ni] = v.w;
            }
        } else {
#pragma unroll
            for (int p = 0; p < 2; ++p) {
                const int kk = (tid >> 5) + p * 8;
                const int ni = (tid & 31) * 4;
                float4 v = *(const float4*)(Bm + (long)(k0 + kk) * ldb + n0 + ni);
                *(float4*)&Bs[kk][ni] = v;
            }
        }
        __syncthreads();

#pragma unroll
        for (int kk = 0; kk < 16; ++kk) {
            float a[8], b[8];
            *(float4*)&a[0] = *(const float4*)&As[kk][ty * 4];
            *(float4*)&a[4] = *(const float4*)&As[kk][64 + ty * 4];
            *(float4*)&b[0] = *(const float4*)&Bs[kk][tx * 4];
            *(float4*)&b[4] = *(const float4*)&Bs[kk][64 + tx * 4];
#pragma unroll
            for (int i = 0; i < 8; ++i)
#pragma unroll
                for (int j = 0; j < 8; ++j)
                    acc[i][j] += a[i] * b[j];
        }
        __syncthreads();
    }

    float bj[8] = {};
    if (BIAS) {
#pragma unroll
        for (int j = 0; j < 4; ++j) bj[j]     = bias[n0 + tx * 4 + j];
#pragma unroll
        for (int j = 0; j < 4; ++j) bj[4 + j] = bias[n0 + 64 + tx * 4 + j];
    }
#pragma unroll
    for (int i = 0; i < 8; ++i) {
        const int m = m0 + (i < 4 ? ty * 4 + i : 64 + ty * 4 + (i - 4));
        if (m >= M) continue;
        float4 o0, o1;
        o0.x = acc[i][0] + bj[0]; o0.y = acc[i][1] + bj[1];
        o0.z = acc[i][2] + bj[2]; o0.w = acc[i][3] + bj[3];
        o1.x = acc[i][4] + bj[4]; o1.y = acc[i][5] + bj[5];
        o1.z = acc[i][6] + bj[6]; o1.w = acc[i][7] + bj[7];
        float* cp = C + (long)m * ldc + n0;
        *(float4*)(cp + tx * 4)      = o0;
        *(float4*)(cp + 64 + tx * 4) = o1;
    }
}

// ---------------------------------------------------------------------------
// bf16 MFMA GEMM (m97 structure): C(f32, MxN) = A(bf16, MxK) * Bt(bf16, NxK)^T
// 128x128 tile, BK=32, 4 waves, 4x4 16x16x32 MFMA tiles per wave.
// ---------------------------------------------------------------------------
template <bool BIAS>
__global__ __launch_bounds__(256)
void gemm_bf16_bt(const unsigned short* __restrict__ A,
                  const unsigned short* __restrict__ Bt,
                  const float* __restrict__ bias,
                  float* __restrict__ C,
                  int M, int N, int K)
{
    __shared__ unsigned short Asm[128 * 32];
    __shared__ unsigned short Bsm[128 * 32];

    const int tid  = threadIdx.x;
    const int lane = tid & 63;
    const int wave = tid >> 6;
    const int m0 = blockIdx.y * 128;
    const int n0 = blockIdx.x * 128;

    const int woffm = (wave & 1) * 64;
    const int woffn = (wave >> 1) * 64;
    const int mrow = lane & 15;
    const int quad = lane >> 4;
    const int ko   = quad * 8;

    v4f acc[4][4] = {};

    const long  arow0 = (long)(m0 + (tid >> 2)) * K + (tid & 3) * 8;
    const long  arow1 = (long)(m0 + 64 + (tid >> 2)) * K + (tid & 3) * 8;
    const long  brow0 = (long)(n0 + (tid >> 2)) * K + (tid & 3) * 8;
    const long  brow1 = (long)(n0 + 64 + (tid >> 2)) * K + (tid & 3) * 8;

    for (int k0 = 0; k0 < K; k0 += 32) {
        ASYNC16(A + arow0 + k0,  &Asm[tid * 8]);
        ASYNC16(A + arow1 + k0,  &Asm[(256 + tid) * 8]);
        ASYNC16(Bt + brow0 + k0, &Bsm[tid * 8]);
        ASYNC16(Bt + brow1 + k0, &Bsm[(256 + tid) * 8]);
        __syncthreads();

        v8s a[4], b[4];
#pragma unroll
        for (int i = 0; i < 4; ++i)
            a[i] = *(const v8s*)&Asm[(woffm + i * 16 + mrow) * 32 + ko];
#pragma unroll
        for (int j = 0; j < 4; ++j)
            b[j] = *(const v8s*)&Bsm[(woffn + j * 16 + mrow) * 32 + ko];
#pragma unroll
        for (int i = 0; i < 4; ++i)
#pragma unroll
            for (int j = 0; j < 4; ++j)
                acc[i][j] = __builtin_amdgcn_mfma_f32_16x16x32_bf16(
                    a[i], b[j], acc[i][j], 0, 0, 0);
        __syncthreads();
    }

    const int col = mrow;
    const int r0  = quad * 4;
#pragma unroll
    for (int j = 0; j < 4; ++j) {
        const int n = n0 + woffn + j * 16 + col;
        const float bv = BIAS ? bias[n] : 0.f;
#pragma unroll
        for (int i = 0; i < 4; ++i) {
            const int mbase = m0 + woffm + i * 16 + r0;
#pragma unroll
            for (int r = 0; r < 4; ++r) {
                const int m = mbase + r;
                if (m < M) C[(long)m * N + n] = acc[i][j][r] + bv;
            }
        }
    }
}

// ---------------------------------------------------------------------------
// Merged bf16x3 split-precision GEMM:
//   C = Ahi*Bhi^T + Ahi*Blo^T + Alo*Bhi^T (+bias)
// Same 128x128/BK=32 structure; 4 staged tiles (32 KB LDS), 48 MFMA/K-step,
// all into ONE accumulator. Replaces 3 separate passes: 1.5x better
// MFMA:staging ratio and writes C exactly once (no read-modify-write).
// ---------------------------------------------------------------------------
template <bool BIAS>
__global__ __launch_bounds__(256)
void gemm_bf16x3_bt(const unsigned short* __restrict__ Ahi,
                    const unsigned short* __restrict__ Alo,
                    const unsigned short* __restrict__ Bhi,
                    const unsigned short* __restrict__ Blo,
                    const float* __restrict__ bias,
                    float* __restrict__ C,
                    int M, int N, int K)
{
    __shared__ unsigned short AsmH[128 * 32];
    __shared__ unsigned short AsmL[128 * 32];
    __shared__ unsigned short BsmH[128 * 32];
    __shared__ unsigned short BsmL[128 * 32];

    const int tid  = threadIdx.x;
    const int lane = tid & 63;
    const int wave = tid >> 6;
    const int m0 = blockIdx.y * 128;
    const int n0 = blockIdx.x * 128;

    const int woffm = (wave & 1) * 64;
    const int woffn = (wave >> 1) * 64;
    const int mrow = lane & 15;
    const int quad = lane >> 4;
    const int ko   = quad * 8;

    v4f acc[4][4] = {};

    const long  arow0 = (long)(m0 + (tid >> 2)) * K + (tid & 3) * 8;
    const long  arow1 = (long)(m0 + 64 + (tid >> 2)) * K + (tid & 3) * 8;
    const long  brow0 = (long)(n0 + (tid >> 2)) * K + (tid & 3) * 8;
    const long  brow1 = (long)(n0 + 64 + (tid >> 2)) * K + (tid & 3) * 8;

    for (int k0 = 0; k0 < K; k0 += 32) {
        ASYNC16(Ahi + arow0 + k0, &AsmH[tid * 8]);
        ASYNC16(Ahi + arow1 + k0, &AsmH[(256 + tid) * 8]);
        ASYNC16(Alo + arow0 + k0, &AsmL[tid * 8]);
        ASYNC16(Alo + arow1 + k0, &AsmL[(256 + tid) * 8]);
        ASYNC16(Bhi + brow0 + k0, &BsmH[tid * 8]);
        ASYNC16(Bhi + brow1 + k0, &BsmH[(256 + tid) * 8]);
        ASYNC16(Blo + brow0 + k0, &BsmL[tid * 8]);
        ASYNC16(Blo + brow1 + k0, &BsmL[(256 + tid) * 8]);
        __syncthreads();

        v8s ah[4], al[4], bh[4], bl[4];
#pragma unroll
        for (int i = 0; i < 4; ++i) {
            const int off = (woffm + i * 16 + mrow) * 32 + ko;
            ah[i] = *(const v8s*)&AsmH[off];
            al[i] = *(const v8s*)&AsmL[off];
        }
#pragma unroll
        for (int j = 0; j < 4; ++j) {
            const int off = (woffn + j * 16 + mrow) * 32 + ko;
            bh[j] = *(const v8s*)&BsmH[off];
            bl[j] = *(const v8s*)&BsmL[off];
        }
#pragma unroll
        for (int i = 0; i < 4; ++i)
#pragma unroll
            for (int j = 0; j < 4; ++j) {
                acc[i][j] = __builtin_amdgcn_mfma_f32_16x16x32_bf16(
                    ah[i], bh[j], acc[i][j], 0, 0, 0);
                acc[i][j] = __builtin_amdgcn_mfma_f32_16x16x32_bf16(
                    ah[i], bl[j], acc[i][j], 0, 0, 0);
                acc[i][j] = __builtin_amdgcn_mfma_f32_16x16x32_bf16(
                    al[i], bh[j], acc[i][j], 0, 0, 0);
            }
        __syncthreads();
    }

    const int col = mrow;
    const int r0  = quad * 4;
#pragma unroll
    for (int j = 0; j < 4; ++j) {
        const int n = n0 + woffn + j * 16 + col;
        const float bv = BIAS ? bias[n] : 0.f;
#pragma unroll
        for (int i = 0; i < 4; ++i) {
            const int mbase = m0 + woffm + i * 16 + r0;
#pragma unroll
            for (int r = 0; r < 4; ++r) {
                const int m = mbase + r;
                if (m < M) C[(long)m * N + n] = acc[i][j][r] + bv;
            }
        }
    }
}

// ---------------------------------------------------------------------------
// Casts
// ---------------------------------------------------------------------------
__global__ __launch_bounds__(256)
void cast_f32_bf16(const float* __restrict__ in, unsigned short* __restrict__ out, long n)
{
    long i = ((long)blockIdx.x * 256 + threadIdx.x) * 8;
    if (i + 8 <= n) {
        float4 v0 = *(const float4*)(in + i);
        float4 v1 = *(const float4*)(in + i + 4);
        ushort4 a, b;
        a.x = f2bf(v0.x); a.y = f2bf(v0.y); a.z = f2bf(v0.z); a.w = f2bf(v0.w);
        b.x = f2bf(v1.x); b.y = f2bf(v1.y); b.z = f2bf(v1.z); b.w = f2bf(v1.w);
        *(ushort4*)(out + i)     = a;
        *(ushort4*)(out + i + 4) = b;
    } else {
        for (; i < n; ++i) out[i] = f2bf(in[i]);
    }
}

// f32 -> (hi bf16, lo bf16) with x ~= hi + lo; lo = bf16(x - f32(hi)).
__global__ __launch_bounds__(256)
void split_cast_hi_lo(const float* __restrict__ in,
                      unsigned short* __restrict__ hi,
                      unsigned short* __restrict__ lo, long n)
{
    long i = ((long)blockIdx.x * 256 + threadIdx.x) * 8;
    if (i + 8 <= n) {
        float4 v0 = *(const float4*)(in + i);
        float4 v1 = *(const float4*)(in + i + 4);
        float x[8] = {v0.x, v0.y, v0.z, v0.w, v1.x, v1.y, v1.z, v1.w};
        unsigned short h[8], l[8];
#pragma unroll
        for (int j = 0; j < 8; ++j) {
            unsigned short hb = f2bf(x[j]);
            h[j] = hb;
            l[j] = f2bf(x[j] - bf2f(hb));
        }
        *(ushort4*)(hi + i)     = make_ushort4(h[0], h[1], h[2], h[3]);
        *(ushort4*)(hi + i + 4) = make_ushort4(h[4], h[5], h[6], h[7]);
        *(ushort4*)(lo + i)     = make_ushort4(l[0], l[1], l[2], l[3]);
        *(ushort4*)(lo + i + 4) = make_ushort4(l[4], l[5], l[6], l[7]);
    } else {
        for (; i < n; ++i) {
            unsigned short hb = f2bf(in[i]);
            hi[i] = hb;
            lo[i] = f2bf(in[i] - bf2f(hb));
        }
    }
}

// W (Kd x Nd f32, row-major) -> Wt (Nd x Kd bf16, row-major)
__global__ __launch_bounds__(256)
void transpose_cast(const float* __restrict__ W, unsigned short* __restrict__ Wt,
                    int Kd, int Nd)
{
    __shared__ float t[32][33];
    const int nb = blockIdx.x * 32, kb = blockIdx.y * 32;
    const int tx = threadIdx.x & 31, ty = threadIdx.x >> 5;
#pragma unroll
    for (int p = 0; p < 4; ++p)
        t[ty + p * 8][tx] = W[(long)(kb + ty + p * 8) * Nd + nb + tx];
    __syncthreads();
#pragma unroll
    for (int p = 0; p < 4; ++p)
        Wt[(long)(nb + ty + p * 8) * Kd + kb + tx] = f2bf(t[tx][ty + p * 8]);
}

// W (Kd x Nd f32) -> WtHi, WtLo (Nd x Kd bf16 each), hi/lo split as above.
__global__ __launch_bounds__(256)
void transpose_split_cast(const float* __restrict__ W,
                          unsigned short* __restrict__ WtHi,
                          unsigned short* __restrict__ WtLo,
                          int Kd, int Nd)
{
    __shared__ float t[32][33];
    const int nb = blockIdx.x * 32, kb = blockIdx.y * 32;
    const int tx = threadIdx.x & 31, ty = threadIdx.x >> 5;
#pragma unroll
    for (int p = 0; p < 4; ++p)
        t[ty + p * 8][tx] = W[(long)(kb + ty + p * 8) * Nd + nb + tx];
    __syncthreads();
#pragma unroll
    for (int p = 0; p < 4; ++p) {
        float x = t[tx][ty + p * 8];
        unsigned short hb = f2bf(x);
        long idx = (long)(nb + ty + p * 8) * Kd + kb + tx;
        WtHi[idx] = hb;
        WtLo[idx] = f2bf(x - bf2f(hb));
    }
}

// ---------------------------------------------------------------------------
// Row 1/||row|| (double) over E_ elements.
// ---------------------------------------------------------------------------
__global__ __launch_bounds__(256)
void row_invnorm(const float* __restrict__ src, double* __restrict__ out,
                 int perBatch, long batchStride)
{
    const int r = blockIdx.x;
    const int b = r / perBatch, i = r % perBatch;
    const float* row = src + (long)b * batchStride + (long)i * E_;
    double s = 0.0;
    for (int c = threadIdx.x; c < E_; c += 256) {
        float v = row[c];
        s += (double)v * (double)v;
    }
    for (int off = 32; off; off >>= 1) s += __shfl_down(s, off, 64);
    __shared__ double wred[4];
    if ((threadIdx.x & 63) == 0) wred[threadIdx.x >> 6] = s;
    __syncthreads();
    if (threadIdx.x == 0)
        out[r] = 1.0 / sqrt(wred[0] + wred[1] + wred[2] + wred[3]);
}

// ---------------------------------------------------------------------------
// Gumbel argmax + scatter, v2: scores precomputed by GEMM into S1.
// One thread per k (256 k per block, grid 16 x H x B). Per thread:
// 100 iterations of {coalesced S1 column load, threefry+f64 gumbel, f64 fma,
// compare}. /tau replaced by *(1/tau): argmax-equivalent for any tau != 0,
// removes 100 f64 divides per thread. Then the same coalesced atomic scatter.
// ---------------------------------------------------------------------------
__global__ __launch_bounds__(256)
void gumbel_argmax_scatter_v2(const float* __restrict__ S1,
                              const float* __restrict__ vp,
                              const double* __restrict__ invqn,
                              const double* __restrict__ invkn,
                              const float* __restrict__ taup,
                              float* __restrict__ outcat)
{
    const int h   = blockIdx.y;
    const int b   = blockIdx.z;
    const int tid = threadIdx.x;
    const int k0  = blockIdx.x * 256;
    const int k   = k0 + tid;

    __shared__ double iqs[NN_];
    __shared__ int    idxs[256];

    for (int e = tid; e < NN_; e += 256) iqs[e] = invqn[b * NN_ + e];
    __syncthreads();

    const double itau = 1.0 / (double)taup[0];
    const double ikd  = invkn[b * S_ + k];
    const float* sp   = S1 + (long)(b * H_ + h) * NN_ * S_ + k;
    const unsigned ibase = (unsigned)((b * H_ + h) * NN_) * (unsigned)S_ + (unsigned)k;

    double best = -1e300;
    int bi = 0;
#pragma unroll 1
    for (int q = 0; q < NN_; ++q) {
        const double g  = gumbel_from_index(ibase + (unsigned)q * (unsigned)S_);
        const double zv = ((double)sp[(long)q * S_] * (iqs[q] * ikd) + g) * itau;
        if (zv > best) { best = zv; bi = q; }
    }
    idxs[tid] = bi;
    __syncthreads();

    for (int kk = 0; kk < 256; ++kk) {
        const int row = idxs[kk];
        const float v = vp[((long)b * S_ + (k0 + kk)) * E_ + h * CH_ + tid];
        atomicAdd(outcat + ((long)b * NQ_ + row) * E_ + h * CH_ + tid, v);
    }
}

// ---------------------------------------------------------------------------
// Row softmax with 1/16 scale folded in.
// ---------------------------------------------------------------------------
__global__ __launch_bounds__(256)
void softmax_rows(float* __restrict__ S2)
{
    const long r = blockIdx.x;
    float* row = S2 + r * (long)S_;
    __shared__ float buf[S_];
    __shared__ float wred[4];
    __shared__ float wsum[4];
    const int tid = threadIdx.x;

    float mx = -1e30f;
    for (int c = tid; c < S_; c += 256) {
        float v = row[c];
        buf[c] = v;
        mx = fmaxf(mx, v);
    }
    for (int off = 32; off; off >>= 1) mx = fmaxf(mx, __shfl_xor(mx, off, 64));
    if ((tid & 63) == 0) wred[tid >> 6] = mx;
    __syncthreads();
    mx = fmaxf(fmaxf(wred[0], wred[1]), fmaxf(wred[2], wred[3]));

    float sum = 0.f;
    for (int c = tid; c < S_; c += 256) {
        float p = __expf((buf[c] - mx) * 0.0625f);
        buf[c] = p;
        sum += p;
    }
    for (int off = 32; off; off >>= 1) sum += __shfl_xor(sum, off, 64);
    if ((tid & 63) == 0) wsum[tid >> 6] = sum;
    __syncthreads();
    sum = wsum[0] + wsum[1] + wsum[2] + wsum[3];
    const float inv = 1.0f / sum;
    for (int c = tid; c < S_; c += 256) row[c] = buf[c] * inv;
}

// ---------------------------------------------------------------------------
// Host-side orchestration.
// Workspace layout (total 668,211,456 B, exactly packed):
//   [0            , 13,107,200 )  qp  f32 1600x2048
//   [13,107,200   , 281,542,656)  kp  f32 32768x2048
//   [281,542,656  , 549,978,112)  vp  f32 32768x2048        (BEFORE vp GEMM:)
//     [281,542,656, 415,760,384)    k_hi bf16 32768x2048  (kp-phase scratch)
//     [415,760,384, 549,978,112)    k_lo bf16 32768x2048  (kp-phase scratch)
//   [549,978,112  , 563,085,312)  outcat f32 1600x2048
//   [563,085,312  , 667,942,912)  S2/S1 f32 64x100x4096     (time-shared:)
//     [563,085,312, 571,473,920)    wk_hi^T bf16 (kp phase only)
//     [571,473,920, 579,862,528)    wk_lo^T bf16 (kp phase only)
//     [563,085,312, 630,194,176)    v_bf16 chunk 16384x2048 (vp phase only)
//     [630,194,176, 638,582,784)    wT1 = wv^T bf16         (vp phase only)
//     S1 (attn1 raw scores, Phase C) then S2 (attn2, Phase D)
//     [563,085,312, 569,901,056)    out_bf16 1664x2048 (after S2 consumed)
//     [569,901,056, 578,289,664)    wT2 = wo^T bf16   (after S2 consumed)
//   [667,942,912  , 667,949,312)  iqn  800 f64
//   [667,949,312  , 668,211,456)  ikn  32768 f64
// ---------------------------------------------------------------------------
extern "C" void kernel_launch(void* const* d_in, const int* in_sizes, int n_in,
                              void* d_out, int out_size, void* d_ws, size_t ws_size,
                              hipStream_t stream)
{
    const float* q   = (const float*)d_in[0];
    const float* k   = (const float*)d_in[1];
    const float* v   = (const float*)d_in[2];
    const float* wq  = (const float*)d_in[3];
    const float* bq  = (const float*)d_in[4];
    const float* wk  = (const float*)d_in[5];
    const float* bk  = (const float*)d_in[6];
    const float* wv  = (const float*)d_in[7];
    const float* bv  = (const float*)d_in[8];
    const float* wo  = (const float*)d_in[9];
    const float* bo  = (const float*)d_in[10];
    const float* tau = (const float*)d_in[11];

    char* ws = (char*)d_ws;
    float*          qp       = (float*)(ws + 0L);
    float*          kp       = (float*)(ws + 13107200L);
    float*          vp       = (float*)(ws + 281542656L);
    unsigned short* k_hi     = (unsigned short*)(ws + 281542656L);   // vp region
    unsigned short* k_lo     = (unsigned short*)(ws + 415760384L);   // vp region
    float*          outcat   = (float*)(ws + 549978112L);
    float*          S2       = (float*)(ws + 563085312L);
    float*          S1       = (float*)(ws + 563085312L);            // alias (Phase C)
    unsigned short* wkThi    = (unsigned short*)(ws + 563085312L);   // S2 region
    unsigned short* wkTlo    = (unsigned short*)(ws + 571473920L);   // S2 region
    unsigned short* v_bf16c  = (unsigned short*)(ws + 563085312L);   // S2 region
    unsigned short* wT1      = (unsigned short*)(ws + 630194176L);   // S2 region
    unsigned short* out_bf16 = (unsigned short*)(ws + 563085312L);
    unsigned short* wT2      = (unsigned short*)(ws + 569901056L);
    double*         iqn      = (double*)(ws + 667942912L);
    double*         ikn      = (double*)(ws + 667949312L);

    const dim3 blk(256);

    // Phase A: kp = k @ wk + bk via merged bf16x3 split-precision MFMA.
    transpose_split_cast<<<dim3(64, 64), blk, 0, stream>>>(wk, wkThi, wkTlo, 2048, 2048);
    split_cast_hi_lo<<<dim3(32768), blk, 0, stream>>>(k, k_hi, k_lo, (long)32768 * 2048);
    gemm_bf16x3_bt<true><<<dim3(16, 256), blk, 0, stream>>>(
        k_hi, k_lo, wkThi, wkTlo, bk, kp, 32768, 2048, 2048);

    // Phase B: qp in f32 (argmax q-side precision; only 1600 rows, cheap).
    gemm_f32<false, true><<<dim3(16, 13, 1), blk, 0, stream>>>(
        q, wq, bq, qp, 1600, 2048, 2048, 2048, 2048, 2048, 0, 0, 0, 0, 0, 0);

    // Phase A2: vp via bf16 MFMA, two M-chunks (scratch in S2 region).
    transpose_cast<<<dim3(64, 64), blk, 0, stream>>>(wv, wT1, 2048, 2048);
    for (int c = 0; c < 2; ++c) {
        cast_f32_bf16<<<dim3(16384), blk, 0, stream>>>(
            v + (long)c * 16384 * 2048, v_bf16c, (long)16384 * 2048);
        gemm_bf16_bt<true><<<dim3(16, 128), blk, 0, stream>>>(
            v_bf16c, wT1, bv, vp + (long)c * 16384 * 2048, 16384, 2048, 2048);
    }

    // Phase C: row norms, attn1 raw scores via batched GEMM, then
    // gumbel argmax + scatter (out1 rows 0..99 of outcat).
    row_invnorm<<<dim3(800), blk, 0, stream>>>(qp, iqn, NN_, (long)NQ_ * E_);
    row_invnorm<<<dim3(32768), blk, 0, stream>>>(kp, ikn, S_, (long)S_ * E_);
    gemm_f32<true, false><<<dim3(32, 1, 64), blk, 0, stream>>>(
        qp, kp, nullptr, S1,
        100, 4096, 256, 2048, 2048, 4096,
        (long)NQ_ * E_, (long)CH_,
        (long)S_ * E_, (long)CH_,
        (long)H_ * NN_ * S_, (long)NN_ * S_);
    hipMemsetAsync(outcat, 0, 13107200, stream);
    gumbel_argmax_scatter_v2<<<dim3(16, 8, 8), blk, 0, stream>>>(
        S1, vp, iqn, ikn, tau, outcat);

    // Phase D: attn2 -> outcat rows 100..199 (S2 overwrites S1 region;
    // stream-ordered after argmax consumed it).
    gemm_f32<true, false><<<dim3(32, 1, 64), blk, 0, stream>>>(
        qp + (long)NN_ * E_, kp, nullptr, S2,
        100, 4096, 256, 2048, 2048, 4096,
        (long)NQ_ * E_, (long)CH_,
        (long)S_ * E_, (long)CH_,
        (long)H_ * NN_ * S_, (long)NN_ * S_);
    softmax_rows<<<dim3(6400), blk, 0, stream>>>(S2);
    gemm_f32<false, false><<<dim3(2, 1, 64), blk, 0, stream>>>(
        S2, vp, nullptr, outcat + (long)NN_ * E_,
        100, 256, 4096, 4096, 2048, 2048,
        (long)H_ * NN_ * S_, (long)NN_ * S_,
        (long)S_ * E_, (long)CH_,
        (long)NQ_ * E_, (long)CH_);

    // Phase E: final projection via bf16 MFMA (S2 region reused for scratch)
    cast_f32_bf16<<<dim3(1600), blk, 0, stream>>>(outcat, out_bf16, (long)1600 * 2048);
    transpose_cast<<<dim3(64, 64), blk, 0, stream>>>(wo, wT2, 2048, 2048);
    gemm_bf16_bt<true><<<dim3(16, 13), blk, 0, stream>>>(
        out_bf16, wT2, bo, (float*)d_out, 1600, 2048, 2048);
}

// Round 4
// 3392.160 us; speedup vs baseline: 2.5128x; 1.1347x over previous
//
#include <hip/hip_runtime.h>

// Problem constants (fixed by setup_inputs)
#define B_   8
#define NQ_  200
#define S_   4096
#define E_   2048
#define H_   8
#define CH_  256     // E/H
#define NN_  100     // n (first-n queries -> gumbel branch)

typedef short v8s  __attribute__((ext_vector_type(8)));
typedef float v4f  __attribute__((ext_vector_type(4)));

// ---------------------------------------------------------------------------
// Threefry-2x32, JAX partitionable scheme: key = (0, 42); per flat index i:
// x = (hi32(i)=0, lo32(i)=i); bits = out0 ^ out1.
// ---------------------------------------------------------------------------
__device__ __forceinline__ unsigned rotl32(unsigned x, int d) {
    return (x << d) | (x >> (32 - d));
}

__device__ __forceinline__ unsigned threefry_bits(unsigned x0, unsigned x1) {
    const unsigned ks0 = 0u;
    const unsigned ks1 = 42u;
    const unsigned ks2 = 0x1BD11BDAu ^ 0u ^ 42u;
    x0 += ks0; x1 += ks1;
#define TFR(d) { x0 += x1; x1 = rotl32(x1, d); x1 ^= x0; }
    TFR(13) TFR(15) TFR(26) TFR(6)
    x0 += ks1; x1 += ks2 + 1u;
    TFR(17) TFR(29) TFR(16) TFR(24)
    x0 += ks2; x1 += ks0 + 2u;
    TFR(13) TFR(15) TFR(26) TFR(6)
    x0 += ks0; x1 += ks1 + 3u;
    TFR(17) TFR(29) TFR(16) TFR(24)
    x0 += ks1; x1 += ks2 + 4u;
    TFR(13) TFR(15) TFR(26) TFR(6)
    x0 += ks2; x1 += ks0 + 5u;
#undef TFR
    return x0 ^ x1;   // partitionable fold for 32-bit draws
}

// Exact replication of jax.random.uniform f32 bit manipulation, then Gumbel in f64.
__device__ __forceinline__ double gumbel_from_index(unsigned i) {
    unsigned bits = threefry_bits(0u, i);
    float f = __uint_as_float((bits >> 9) | 0x3F800000u) - 1.0f;   // [0,1)
    const float minv = 1e-6f;
    const float maxv = (float)(1.0 - 1e-6);
    float span = __fsub_rn(maxv, minv);
    float u = __fadd_rn(__fmul_rn(f, span), minv);   // mul then add, unfused like XLA
    u = fmaxf(minv, u);
    double lg = log((double)u);
    return -log(-lg);
}

// f32 -> bf16 (RNE)
__device__ __forceinline__ unsigned short f2bf(float f) {
    unsigned u = __float_as_uint(f);
    unsigned r = (u + 0x7FFFu + ((u >> 16) & 1u)) >> 16;
    return (unsigned short)r;
}

__device__ __forceinline__ float bf2f(unsigned short h) {
    return __uint_as_float(((unsigned)h) << 16);
}

// async global->LDS, 16B per lane
#define ASYNC16(g, l)                                                          \
    __builtin_amdgcn_global_load_lds(                                          \
        (const __attribute__((address_space(1))) unsigned*)(g),                \
        (__attribute__((address_space(3))) unsigned*)(l), 16, 0, 0)

// XCD-aware bijective block swizzle over a flattened 2D grid (nwg % 8 == 0).
__device__ __forceinline__ void xcd_swizzle(int& bx, int& by) {
    const int nwg = gridDim.x * gridDim.y;
    int flat = blockIdx.y * gridDim.x + blockIdx.x;
    if ((nwg & 7) == 0) {
        const int cpx = nwg >> 3;
        flat = (flat & 7) * cpx + (flat >> 3);
    }
    bx = flat % gridDim.x;
    by = flat / gridDim.x;
}

// ---------------------------------------------------------------------------
// Generic tiled f32 GEMM: C = A * op(B) (+bias), 128x128 tile, 8x8 microtile.
// TB=false: B is KxN (ldb);  TB=true: B is NxK (ldb), i.e. C = A * B^T.
// z decomposition: zc = blockIdx.z; kc = zc>>6 (K-chunk for ATOMIC split-K);
// z = zc&63 -> zo=z>>3, zi=z&7 batch offsets.
// ATOMIC: epilogue atomicAdd (no bias), A/B advanced by kc*K.
// ---------------------------------------------------------------------------
template <bool TB, bool BIAS, bool ATOMIC>
__global__ __launch_bounds__(256)
void gemm_f32(const float* __restrict__ A, const float* __restrict__ Bm,
              const float* __restrict__ bias, float* __restrict__ C,
              int M, int N, int K, int lda, int ldb, int ldc,
              long saO, long saI, long sbO, long sbI, long scO, long scI)
{
    const int zc = blockIdx.z;
    const int kc = zc >> 6;
    const int z  = zc & 63;
    const int zo = z >> 3, zi = z & 7;
    A  += (long)zo * saO + (long)zi * saI + (long)kc * K;
    Bm += (long)zo * sbO + (long)zi * sbI + (TB ? (long)kc * K : (long)kc * K * ldb);
    C  += (long)zo * scO + (long)zi * scI;

    const int tid = threadIdx.x;
    const int n0  = blockIdx.x * 128;
    const int m0  = blockIdx.y * 128;

    __shared__ float As[16][132];
    __shared__ float Bs[16][132];

    float acc[8][8] = {};

    const int tx = tid & 15, ty = tid >> 4;

    for (int k0 = 0; k0 < K; k0 += 16) {
        // ---- stage A tile (transposed): As[kk][m]
        {
            const int kk = (tid & 3) * 4;
#pragma unroll
            for (int p = 0; p < 2; ++p) {
                const int mi = (tid >> 2) + p * 64;
                const int m  = m0 + mi;
                float4 v = make_float4(0.f, 0.f, 0.f, 0.f);
                if (m < M) v = *(const float4*)(A + (long)m * lda + k0 + kk);
                As[kk + 0][mi] = v.x; As[kk + 1][mi] = v.y;
                As[kk + 2][mi] = v.z; As[kk + 3][mi] = v.w;
            }
        }
        // ---- stage B tile: Bs[kk][n]
        if (TB) {
            const int kk = (tid & 3) * 4;
#pragma unroll
            for (int p = 0; p < 2; ++p) {
                const int ni = (tid >> 2) + p * 64;
                const int nn = n0 + ni;
                float4 v = make_float4(0.f, 0.f, 0.f, 0.f);
                if (nn < N) v = *(const float4*)(Bm + (long)nn * ldb + k0 + kk);
                Bs[kk + 0][ni] = v.x; Bs[kk + 1][ni] = v.y;
                Bs[kk + 2][ni] = v.z; Bs[kk + 3][ni] = v.w;
            }
        } else {
#pragma unroll
            for (int p = 0; p < 2; ++p) {
                const int kk = (tid >> 5) + p * 8;
                const int ni = (tid & 31) * 4;
                float4 v = *(const float4*)(Bm + (long)(k0 + kk) * ldb + n0 + ni);
                *(float4*)&Bs[kk][ni] = v;
            }
        }
        __syncthreads();

#pragma unroll
        for (int kk = 0; kk < 16; ++kk) {
            float a[8], b[8];
            *(float4*)&a[0] = *(const float4*)&As[kk][ty * 4];
            *(float4*)&a[4] = *(const float4*)&As[kk][64 + ty * 4];
            *(float4*)&b[0] = *(const float4*)&Bs[kk][tx * 4];
            *(float4*)&b[4] = *(const float4*)&Bs[kk][64 + tx * 4];
#pragma unroll
            for (int i = 0; i < 8; ++i)
#pragma unroll
                for (int j = 0; j < 8; ++j)
                    acc[i][j] += a[i] * b[j];
        }
        __syncthreads();
    }

    float bj[8] = {};
    if (BIAS) {
#pragma unroll
        for (int j = 0; j < 4; ++j) bj[j]     = bias[n0 + tx * 4 + j];
#pragma unroll
        for (int j = 0; j < 4; ++j) bj[4 + j] = bias[n0 + 64 + tx * 4 + j];
    }
#pragma unroll
    for (int i = 0; i < 8; ++i) {
        const int m = m0 + (i < 4 ? ty * 4 + i : 64 + ty * 4 + (i - 4));
        if (m >= M) continue;
        float* cp = C + (long)m * ldc + n0;
        if (ATOMIC) {
#pragma unroll
            for (int j = 0; j < 4; ++j) atomicAdd(cp + tx * 4 + j,      acc[i][j]);
#pragma unroll
            for (int j = 0; j < 4; ++j) atomicAdd(cp + 64 + tx * 4 + j, acc[i][4 + j]);
        } else {
            float4 o0, o1;
            o0.x = acc[i][0] + bj[0]; o0.y = acc[i][1] + bj[1];
            o0.z = acc[i][2] + bj[2]; o0.w = acc[i][3] + bj[3];
            o1.x = acc[i][4] + bj[4]; o1.y = acc[i][5] + bj[5];
            o1.z = acc[i][6] + bj[6]; o1.w = acc[i][7] + bj[7];
            *(float4*)(cp + tx * 4)      = o0;
            *(float4*)(cp + 64 + tx * 4) = o1;
        }
    }
}

// ---------------------------------------------------------------------------
// bf16 MFMA GEMM (m97 structure): C(f32, MxN) = A(bf16, MxK) * Bt(bf16, NxK)^T
// 128x128 tile, BK=32, 4 waves, 4x4 16x16x32 MFMA tiles per wave.
// A-row staging clamped to M-1 (allows M not multiple of 128 without pad).
// ---------------------------------------------------------------------------
template <bool BIAS>
__global__ __launch_bounds__(256)
void gemm_bf16_bt(const unsigned short* __restrict__ A,
                  const unsigned short* __restrict__ Bt,
                  const float* __restrict__ bias,
                  float* __restrict__ C,
                  int M, int N, int K)
{
    __shared__ unsigned short Asm[128 * 32];
    __shared__ unsigned short Bsm[128 * 32];

    int bx, by;
    xcd_swizzle(bx, by);

    const int tid  = threadIdx.x;
    const int lane = tid & 63;
    const int wave = tid >> 6;
    const int m0 = by * 128;
    const int n0 = bx * 128;

    const int woffm = (wave & 1) * 64;
    const int woffn = (wave >> 1) * 64;
    const int mrow = lane & 15;
    const int quad = lane >> 4;
    const int ko   = quad * 8;

    v4f acc[4][4] = {};

    const int ar0 = min(m0 + (tid >> 2), M - 1);
    const int ar1 = min(m0 + 64 + (tid >> 2), M - 1);
    const long  arow0 = (long)ar0 * K + (tid & 3) * 8;
    const long  arow1 = (long)ar1 * K + (tid & 3) * 8;
    const long  brow0 = (long)(n0 + (tid >> 2)) * K + (tid & 3) * 8;
    const long  brow1 = (long)(n0 + 64 + (tid >> 2)) * K + (tid & 3) * 8;

    for (int k0 = 0; k0 < K; k0 += 32) {
        ASYNC16(A + arow0 + k0,  &Asm[tid * 8]);
        ASYNC16(A + arow1 + k0,  &Asm[(256 + tid) * 8]);
        ASYNC16(Bt + brow0 + k0, &Bsm[tid * 8]);
        ASYNC16(Bt + brow1 + k0, &Bsm[(256 + tid) * 8]);
        __syncthreads();

        v8s a[4], b[4];
#pragma unroll
        for (int i = 0; i < 4; ++i)
            a[i] = *(const v8s*)&Asm[(woffm + i * 16 + mrow) * 32 + ko];
#pragma unroll
        for (int j = 0; j < 4; ++j)
            b[j] = *(const v8s*)&Bsm[(woffn + j * 16 + mrow) * 32 + ko];
#pragma unroll
        for (int i = 0; i < 4; ++i)
#pragma unroll
            for (int j = 0; j < 4; ++j)
                acc[i][j] = __builtin_amdgcn_mfma_f32_16x16x32_bf16(
                    a[i], b[j], acc[i][j], 0, 0, 0);
        __syncthreads();
    }

    const int col = mrow;
    const int r0  = quad * 4;
#pragma unroll
    for (int j = 0; j < 4; ++j) {
        const int n = n0 + woffn + j * 16 + col;
        const float bv = BIAS ? bias[n] : 0.f;
#pragma unroll
        for (int i = 0; i < 4; ++i) {
            const int mbase = m0 + woffm + i * 16 + r0;
#pragma unroll
            for (int r = 0; r < 4; ++r) {
                const int m = mbase + r;
                if (m < M) C[(long)m * N + n] = acc[i][j][r] + bv;
            }
        }
    }
}

// ---------------------------------------------------------------------------
// Merged bf16x3 split-precision GEMM:
//   out = Ahi*Bhi^T + Ahi*Blo^T + Alo*Bhi^T (+bias)
// SPLITOUT=false: write C f32.  SPLITOUT=true: write (Chi, Clo) bf16 planes
// with val ~= hi + lo (residual ~2^-17 rel) — feeds downstream bf16x3 GEMMs
// with no f32 materialization.
// ---------------------------------------------------------------------------
template <bool BIAS, bool SPLITOUT>
__global__ __launch_bounds__(256)
void gemm_bf16x3_bt(const unsigned short* __restrict__ Ahi,
                    const unsigned short* __restrict__ Alo,
                    const unsigned short* __restrict__ Bhi,
                    const unsigned short* __restrict__ Blo,
                    const float* __restrict__ bias,
                    float* __restrict__ C,
                    unsigned short* __restrict__ Chi,
                    unsigned short* __restrict__ Clo,
                    int M, int N, int K)
{
    __shared__ unsigned short AsmH[128 * 32];
    __shared__ unsigned short AsmL[128 * 32];
    __shared__ unsigned short BsmH[128 * 32];
    __shared__ unsigned short BsmL[128 * 32];

    int bx, by;
    xcd_swizzle(bx, by);

    const int tid  = threadIdx.x;
    const int lane = tid & 63;
    const int wave = tid >> 6;
    const int m0 = by * 128;
    const int n0 = bx * 128;

    const int woffm = (wave & 1) * 64;
    const int woffn = (wave >> 1) * 64;
    const int mrow = lane & 15;
    const int quad = lane >> 4;
    const int ko   = quad * 8;

    v4f acc[4][4] = {};

    const int ar0 = min(m0 + (tid >> 2), M - 1);
    const int ar1 = min(m0 + 64 + (tid >> 2), M - 1);
    const long  arow0 = (long)ar0 * K + (tid & 3) * 8;
    const long  arow1 = (long)ar1 * K + (tid & 3) * 8;
    const long  brow0 = (long)(n0 + (tid >> 2)) * K + (tid & 3) * 8;
    const long  brow1 = (long)(n0 + 64 + (tid >> 2)) * K + (tid & 3) * 8;

    for (int k0 = 0; k0 < K; k0 += 32) {
        ASYNC16(Ahi + arow0 + k0, &AsmH[tid * 8]);
        ASYNC16(Ahi + arow1 + k0, &AsmH[(256 + tid) * 8]);
        ASYNC16(Alo + arow0 + k0, &AsmL[tid * 8]);
        ASYNC16(Alo + arow1 + k0, &AsmL[(256 + tid) * 8]);
        ASYNC16(Bhi + brow0 + k0, &BsmH[tid * 8]);
        ASYNC16(Bhi + brow1 + k0, &BsmH[(256 + tid) * 8]);
        ASYNC16(Blo + brow0 + k0, &BsmL[tid * 8]);
        ASYNC16(Blo + brow1 + k0, &BsmL[(256 + tid) * 8]);
        __syncthreads();

        v8s ah[4], al[4], bh[4], bl[4];
#pragma unroll
        for (int i = 0; i < 4; ++i) {
            const int off = (woffm + i * 16 + mrow) * 32 + ko;
            ah[i] = *(const v8s*)&AsmH[off];
            al[i] = *(const v8s*)&AsmL[off];
        }
#pragma unroll
        for (int j = 0; j < 4; ++j) {
            const int off = (woffn + j * 16 + mrow) * 32 + ko;
            bh[j] = *(const v8s*)&BsmH[off];
            bl[j] = *(const v8s*)&BsmL[off];
        }
#pragma unroll
        for (int i = 0; i < 4; ++i)
#pragma unroll
            for (int j = 0; j < 4; ++j) {
                acc[i][j] = __builtin_amdgcn_mfma_f32_16x16x32_bf16(
                    ah[i], bh[j], acc[i][j], 0, 0, 0);
                acc[i][j] = __builtin_amdgcn_mfma_f32_16x16x32_bf16(
                    ah[i], bl[j], acc[i][j], 0, 0, 0);
                acc[i][j] = __builtin_amdgcn_mfma_f32_16x16x32_bf16(
                    al[i], bh[j], acc[i][j], 0, 0, 0);
            }
        __syncthreads();
    }

    const int col = mrow;
    const int r0  = quad * 4;
#pragma unroll
    for (int j = 0; j < 4; ++j) {
        const int n = n0 + woffn + j * 16 + col;
        const float bv = BIAS ? bias[n] : 0.f;
#pragma unroll
        for (int i = 0; i < 4; ++i) {
            const int mbase = m0 + woffm + i * 16 + r0;
#pragma unroll
            for (int r = 0; r < 4; ++r) {
                const int m = mbase + r;
                if (m < M) {
                    const float o = acc[i][j][r] + bv;
                    if (SPLITOUT) {
                        const unsigned short hb = f2bf(o);
                        Chi[(long)m * N + n] = hb;
                        Clo[(long)m * N + n] = f2bf(o - bf2f(hb));
                    } else {
                        C[(long)m * N + n] = o;
                    }
                }
            }
        }
    }
}

// ---------------------------------------------------------------------------
// Batched per-head attention-score GEMM, bf16x3 split precision:
//   S[z][m][n] = qp[b, qRowOff+m, hc] . kp[b, n, hc]   (hc = head h cols)
// grid (S_/128, 1, 64), z = b*8 + h. M=100 (one m-tile), K=CH_=256.
// A-row staging clamped to global row 1599 (qp has 1600 rows).
// ---------------------------------------------------------------------------
__global__ __launch_bounds__(256)
void attn_scores_bf16x3(const unsigned short* __restrict__ Qhi,
                        const unsigned short* __restrict__ Qlo,
                        const unsigned short* __restrict__ Khi,
                        const unsigned short* __restrict__ Klo,
                        float* __restrict__ Sout, int qRowOff)
{
    __shared__ unsigned short AsmH[128 * 32];
    __shared__ unsigned short AsmL[128 * 32];
    __shared__ unsigned short BsmH[128 * 32];
    __shared__ unsigned short BsmL[128 * 32];

    const int z = blockIdx.z;
    const int b = z >> 3, h = z & 7;
    const int n0 = blockIdx.x * 128;

    const int tid  = threadIdx.x;
    const int lane = tid & 63;
    const int wave = tid >> 6;

    const int woffm = (wave & 1) * 64;
    const int woffn = (wave >> 1) * 64;
    const int mrow = lane & 15;
    const int quad = lane >> 4;
    const int ko   = quad * 8;

    v4f acc[4][4] = {};

    const int ar0 = min(b * NQ_ + qRowOff + (tid >> 2), B_ * NQ_ - 1);
    const int ar1 = min(b * NQ_ + qRowOff + 64 + (tid >> 2), B_ * NQ_ - 1);
    const long abase0 = (long)ar0 * E_ + h * CH_ + (tid & 3) * 8;
    const long abase1 = (long)ar1 * E_ + h * CH_ + (tid & 3) * 8;
    const long bbase0 = (long)((long)b * S_ + n0 + (tid >> 2)) * E_ + h * CH_ + (tid & 3) * 8;
    const long bbase1 = (long)((long)b * S_ + n0 + 64 + (tid >> 2)) * E_ + h * CH_ + (tid & 3) * 8;

    for (int k0 = 0; k0 < CH_; k0 += 32) {
        ASYNC16(Qhi + abase0 + k0, &AsmH[tid * 8]);
        ASYNC16(Qhi + abase1 + k0, &AsmH[(256 + tid) * 8]);
        ASYNC16(Qlo + abase0 + k0, &AsmL[tid * 8]);
        ASYNC16(Qlo + abase1 + k0, &AsmL[(256 + tid) * 8]);
        ASYNC16(Khi + bbase0 + k0, &BsmH[tid * 8]);
        ASYNC16(Khi + bbase1 + k0, &BsmH[(256 + tid) * 8]);
        ASYNC16(Klo + bbase0 + k0, &BsmL[tid * 8]);
        ASYNC16(Klo + bbase1 + k0, &BsmL[(256 + tid) * 8]);
        __syncthreads();

        v8s ah[4], al[4], bh[4], bl[4];
#pragma unroll
        for (int i = 0; i < 4; ++i) {
            const int off = (woffm + i * 16 + mrow) * 32 + ko;
            ah[i] = *(const v8s*)&AsmH[off];
            al[i] = *(const v8s*)&AsmL[off];
        }
#pragma unroll
        for (int j = 0; j < 4; ++j) {
            const int off = (woffn + j * 16 + mrow) * 32 + ko;
            bh[j] = *(const v8s*)&BsmH[off];
            bl[j] = *(const v8s*)&BsmL[off];
        }
#pragma unroll
        for (int i = 0; i < 4; ++i)
#pragma unroll
            for (int j = 0; j < 4; ++j) {
                acc[i][j] = __builtin_amdgcn_mfma_f32_16x16x32_bf16(
                    ah[i], bh[j], acc[i][j], 0, 0, 0);
                acc[i][j] = __builtin_amdgcn_mfma_f32_16x16x32_bf16(
                    ah[i], bl[j], acc[i][j], 0, 0, 0);
                acc[i][j] = __builtin_amdgcn_mfma_f32_16x16x32_bf16(
                    al[i], bh[j], acc[i][j], 0, 0, 0);
            }
        __syncthreads();
    }

    float* Cb = Sout + (long)z * NN_ * S_;
    const int col = mrow;
    const int r0  = quad * 4;
#pragma unroll
    for (int j = 0; j < 4; ++j) {
        const int n = n0 + woffn + j * 16 + col;
#pragma unroll
        for (int i = 0; i < 4; ++i) {
            const int mbase = woffm + i * 16 + r0;
#pragma unroll
            for (int r = 0; r < 4; ++r) {
                const int m = mbase + r;
                if (m < NN_) Cb[(long)m * S_ + n] = acc[i][j][r];
            }
        }
    }
}

// ---------------------------------------------------------------------------
// Casts
// ---------------------------------------------------------------------------
__global__ __launch_bounds__(256)
void cast_f32_bf16(const float* __restrict__ in, unsigned short* __restrict__ out, long n)
{
    long i = ((long)blockIdx.x * 256 + threadIdx.x) * 8;
    if (i + 8 <= n) {
        float4 v0 = *(const float4*)(in + i);
        float4 v1 = *(const float4*)(in + i + 4);
        ushort4 a, b;
        a.x = f2bf(v0.x); a.y = f2bf(v0.y); a.z = f2bf(v0.z); a.w = f2bf(v0.w);
        b.x = f2bf(v1.x); b.y = f2bf(v1.y); b.z = f2bf(v1.z); b.w = f2bf(v1.w);
        *(ushort4*)(out + i)     = a;
        *(ushort4*)(out + i + 4) = b;
    } else {
        for (; i < n; ++i) out[i] = f2bf(in[i]);
    }
}

// f32 -> (hi bf16, lo bf16) with x ~= hi + lo; lo = bf16(x - f32(hi)).
__global__ __launch_bounds__(256)
void split_cast_hi_lo(const float* __restrict__ in,
                      unsigned short* __restrict__ hi,
                      unsigned short* __restrict__ lo, long n)
{
    long i = ((long)blockIdx.x * 256 + threadIdx.x) * 8;
    if (i + 8 <= n) {
        float4 v0 = *(const float4*)(in + i);
        float4 v1 = *(const float4*)(in + i + 4);
        float x[8] = {v0.x, v0.y, v0.z, v0.w, v1.x, v1.y, v1.z, v1.w};
        unsigned short h[8], l[8];
#pragma unroll
        for (int j = 0; j < 8; ++j) {
            unsigned short hb = f2bf(x[j]);
            h[j] = hb;
            l[j] = f2bf(x[j] - bf2f(hb));
        }
        *(ushort4*)(hi + i)     = make_ushort4(h[0], h[1], h[2], h[3]);
        *(ushort4*)(hi + i + 4) = make_ushort4(h[4], h[5], h[6], h[7]);
        *(ushort4*)(lo + i)     = make_ushort4(l[0], l[1], l[2], l[3]);
        *(ushort4*)(lo + i + 4) = make_ushort4(l[4], l[5], l[6], l[7]);
    } else {
        for (; i < n; ++i) {
            unsigned short hb = f2bf(in[i]);
            hi[i] = hb;
            lo[i] = f2bf(in[i] - bf2f(hb));
        }
    }
}

// W (Kd x Nd f32, row-major) -> Wt (Nd x Kd bf16, row-major)
__global__ __launch_bounds__(256)
void transpose_cast(const float* __restrict__ W, unsigned short* __restrict__ Wt,
                    int Kd, int Nd)
{
    __shared__ float t[32][33];
    const int nb = blockIdx.x * 32, kb = blockIdx.y * 32;
    const int tx = threadIdx.x & 31, ty = threadIdx.x >> 5;
#pragma unroll
    for (int p = 0; p < 4; ++p)
        t[ty + p * 8][tx] = W[(long)(kb + ty + p * 8) * Nd + nb + tx];
    __syncthreads();
#pragma unroll
    for (int p = 0; p < 4; ++p)
        Wt[(long)(nb + ty + p * 8) * Kd + kb + tx] = f2bf(t[tx][ty + p * 8]);
}

// W (Kd x Nd f32) -> WtHi, WtLo (Nd x Kd bf16 each), hi/lo split as above.
__global__ __launch_bounds__(256)
void transpose_split_cast(const float* __restrict__ W,
                          unsigned short* __restrict__ WtHi,
                          unsigned short* __restrict__ WtLo,
                          int Kd, int Nd)
{
    __shared__ float t[32][33];
    const int nb = blockIdx.x * 32, kb = blockIdx.y * 32;
    const int tx = threadIdx.x & 31, ty = threadIdx.x >> 5;
#pragma unroll
    for (int p = 0; p < 4; ++p)
        t[ty + p * 8][tx] = W[(long)(kb + ty + p * 8) * Nd + nb + tx];
    __syncthreads();
#pragma unroll
    for (int p = 0; p < 4; ++p) {
        float x = t[tx][ty + p * 8];
        unsigned short hb = f2bf(x);
        long idx = (long)(nb + ty + p * 8) * Kd + kb + tx;
        WtHi[idx] = hb;
        WtLo[idx] = f2bf(x - bf2f(hb));
    }
}

// ---------------------------------------------------------------------------
// Row 1/||row|| (double) over E_ elements — f32 source.
// ---------------------------------------------------------------------------
__global__ __launch_bounds__(256)
void row_invnorm(const float* __restrict__ src, double* __restrict__ out,
                 int perBatch, long batchStride)
{
    const int r = blockIdx.x;
    const int b = r / perBatch, i = r % perBatch;
    const float* row = src + (long)b * batchStride + (long)i * E_;
    double s = 0.0;
    for (int c = threadIdx.x; c < E_; c += 256) {
        float v = row[c];
        s += (double)v * (double)v;
    }
    for (int off = 32; off; off >>= 1) s += __shfl_down(s, off, 64);
    __shared__ double wred[4];
    if ((threadIdx.x & 63) == 0) wred[threadIdx.x >> 6] = s;
    __syncthreads();
    if (threadIdx.x == 0)
        out[r] = 1.0 / sqrt(wred[0] + wred[1] + wred[2] + wred[3]);
}

// Same but from (hi, lo) bf16 planes, contiguous rows.
__global__ __launch_bounds__(256)
void row_invnorm_hl(const unsigned short* __restrict__ hi,
                    const unsigned short* __restrict__ lo,
                    double* __restrict__ out)
{
    const long r = blockIdx.x;
    const long base = r * E_ + (long)threadIdx.x * 8;
    v8s vh = *(const v8s*)(hi + base);
    v8s vl = *(const v8s*)(lo + base);
    double s = 0.0;
#pragma unroll
    for (int j = 0; j < 8; ++j) {
        float v = bf2f((unsigned short)vh[j]) + bf2f((unsigned short)vl[j]);
        s += (double)v * (double)v;
    }
    for (int off = 32; off; off >>= 1) s += __shfl_down(s, off, 64);
    __shared__ double wred[4];
    if ((threadIdx.x & 63) == 0) wred[threadIdx.x >> 6] = s;
    __syncthreads();
    if (threadIdx.x == 0)
        out[r] = 1.0 / sqrt(wred[0] + wred[1] + wred[2] + wred[3]);
}

// ---------------------------------------------------------------------------
// Gumbel argmax + scatter, v3: LDS accumulation instead of global atomics.
// grid (4, H, B): block owns k-chunk of 1024 for one (b,h).
// Phase 1: per-k argmax over q of (S1*iq*ik + gumbel)*itau  (4 passes x 256 k).
// Phase 2: serial scatter of vp rows into LDS accum[100][256] (no atomics).
// Phase 3: one atomicAdd flush per (row, channel): 26 MB total atomic traffic
// vs 268 MB in v2.
// ---------------------------------------------------------------------------
__global__ __launch_bounds__(256)
void gumbel_argmax_scatter_v3(const float* __restrict__ S1,
                              const float* __restrict__ vp,
                              const double* __restrict__ invqn,
                              const double* __restrict__ invkn,
                              const float* __restrict__ taup,
                              float* __restrict__ outcat)
{
    const int kc  = blockIdx.x;            // 0..3
    const int h   = blockIdx.y;
    const int b   = blockIdx.z;
    const int tid = threadIdx.x;
    const int k0  = kc * 1024;

    __shared__ float  accum[NN_][256];     // 100 KB
    __shared__ int    idxs[1024];
    __shared__ double iqs[NN_];

    for (int e = tid; e < NN_; e += 256) iqs[e] = invqn[b * NN_ + e];
#pragma unroll
    for (int r = tid; r < NN_ * 256; r += 256) ((float*)accum)[r] = 0.f;
    __syncthreads();

    const double itau = 1.0 / (double)taup[0];
    const float* S1b = S1 + (long)(b * H_ + h) * NN_ * S_;

    for (int p = 0; p < 4; ++p) {
        const int k = k0 + p * 256 + tid;
        const double ikd = invkn[b * S_ + k];
        const unsigned ibase = (unsigned)((b * H_ + h) * NN_) * (unsigned)S_ + (unsigned)k;
        double best = -1e300;
        int bi = 0;
#pragma unroll 1
        for (int q = 0; q < NN_; ++q) {
            const double g  = gumbel_from_index(ibase + (unsigned)q * (unsigned)S_);
            const double zv = ((double)S1b[(long)q * S_ + k] * (iqs[q] * ikd) + g) * itau;
            if (zv > best) { best = zv; bi = q; }
        }
        idxs[p * 256 + tid] = bi;
    }
    __syncthreads();

    const float* vrow = vp + ((long)b * S_ + k0) * E_ + h * CH_ + tid;
#pragma unroll 4
    for (int kk = 0; kk < 1024; ++kk) {
        accum[idxs[kk]][tid] += vrow[(long)kk * E_];
    }
    __syncthreads();

    for (int q = 0; q < NN_; ++q)
        atomicAdd(outcat + ((long)b * NQ_ + q) * E_ + h * CH_ + tid, accum[q][tid]);
}

// ---------------------------------------------------------------------------
// Row softmax with 1/16 scale folded in.
// ---------------------------------------------------------------------------
__global__ __launch_bounds__(256)
void softmax_rows(float* __restrict__ S2)
{
    const long r = blockIdx.x;
    float* row = S2 + r * (long)S_;
    __shared__ float buf[S_];
    __shared__ float wred[4];
    __shared__ float wsum[4];
    const int tid = threadIdx.x;

    float mx = -1e30f;
    for (int c = tid; c < S_; c += 256) {
        float v = row[c];
        buf[c] = v;
        mx = fmaxf(mx, v);
    }
    for (int off = 32; off; off >>= 1) mx = fmaxf(mx, __shfl_xor(mx, off, 64));
    if ((tid & 63) == 0) wred[tid >> 6] = mx;
    __syncthreads();
    mx = fmaxf(fmaxf(wred[0], wred[1]), fmaxf(wred[2], wred[3]));

    float sum = 0.f;
    for (int c = tid; c < S_; c += 256) {
        float p = __expf((buf[c] - mx) * 0.0625f);
        buf[c] = p;
        sum += p;
    }
    for (int off = 32; off; off >>= 1) sum += __shfl_xor(sum, off, 64);
    if ((tid & 63) == 0) wsum[tid >> 6] = sum;
    __syncthreads();
    sum = wsum[0] + wsum[1] + wsum[2] + wsum[3];
    const float inv = 1.0f / sum;
    for (int c = tid; c < S_; c += 256) row[c] = buf[c] * inv;
}

// ---------------------------------------------------------------------------
// Host-side orchestration.
// Workspace layout (total 668,211,456 B, exactly packed):
//   [0            , 13,107,200 )  qp_hi bf16 1600x2048 (6,553,600) + qp_lo
//   [13,107,200   , 281,542,656)  kp_hi bf16 32768x2048 @13,107,200;
//                                 kp_lo @147,324,928
//   [281,542,656  , 549,978,112)  vp f32 32768x2048      (BEFORE vp GEMM:)
//     [281,542,656, 415,760,384)    k_hi bf16 (kp-phase scratch)
//     [415,760,384, 549,978,112)    k_lo bf16 (kp-phase scratch)
//   [549,978,112  , 563,085,312)  outcat f32 1600x2048   (BEFORE memset:)
//     qpf f32 1600x2048 (qp-phase scratch; split/invnorm consume, then memset)
//   [563,085,312  , 667,942,912)  S region f32 64x100x4096 (time-shared:)
//     kp phase:  wk_hi^T @563,085,312 (8,388,608), wk_lo^T @571,473,920
//     vp phase:  v_bf16 chunk 16384x2048 @563,085,312 (67,108,864),
//                wT1 = wv^T @630,194,176
//     S1 (Phase C) then S2 (Phase D)
//     Phase E:   out_bf16 1664x2048 @563,085,312, wT2 = wo^T @569,901,056
//   [667,942,912  , 667,949,312)  iqn  800 f64
//   [667,949,312  , 668,211,456)  ikn  32768 f64
// ---------------------------------------------------------------------------
extern "C" void kernel_launch(void* const* d_in, const int* in_sizes, int n_in,
                              void* d_out, int out_size, void* d_ws, size_t ws_size,
                              hipStream_t stream)
{
    const float* q   = (const float*)d_in[0];
    const float* k   = (const float*)d_in[1];
    const float* v   = (const float*)d_in[2];
    const float* wq  = (const float*)d_in[3];
    const float* bq  = (const float*)d_in[4];
    const float* wk  = (const float*)d_in[5];
    const float* bk  = (const float*)d_in[6];
    const float* wv  = (const float*)d_in[7];
    const float* bv  = (const float*)d_in[8];
    const float* wo  = (const float*)d_in[9];
    const float* bo  = (const float*)d_in[10];
    const float* tau = (const float*)d_in[11];

    char* ws = (char*)d_ws;
    unsigned short* qp_hi    = (unsigned short*)(ws + 0L);
    unsigned short* qp_lo    = (unsigned short*)(ws + 6553600L);
    unsigned short* kp_hi    = (unsigned short*)(ws + 13107200L);
    unsigned short* kp_lo    = (unsigned short*)(ws + 147324928L);
    float*          vp       = (float*)(ws + 281542656L);
    unsigned short* k_hi     = (unsigned short*)(ws + 281542656L);   // vp region
    unsigned short* k_lo     = (unsigned short*)(ws + 415760384L);   // vp region
    float*          outcat   = (float*)(ws + 549978112L);
    float*          qpf      = (float*)(ws + 549978112L);            // outcat region
    float*          Sreg     = (float*)(ws + 563085312L);
    unsigned short* wkThi    = (unsigned short*)(ws + 563085312L);   // S region
    unsigned short* wkTlo    = (unsigned short*)(ws + 571473920L);   // S region
    unsigned short* v_bf16c  = (unsigned short*)(ws + 563085312L);   // S region
    unsigned short* wT1      = (unsigned short*)(ws + 630194176L);   // S region
    unsigned short* out_bf16 = (unsigned short*)(ws + 563085312L);
    unsigned short* wT2      = (unsigned short*)(ws + 569901056L);
    double*         iqn      = (double*)(ws + 667942912L);
    double*         ikn      = (double*)(ws + 667949312L);

    const dim3 blk(256);

    // Phase K: kp = k @ wk + bk via merged bf16x3 MFMA, epilogue emits
    // (kp_hi, kp_lo) bf16 planes directly (no f32 kp ever materialized).
    transpose_split_cast<<<dim3(64, 64), blk, 0, stream>>>(wk, wkThi, wkTlo, 2048, 2048);
    split_cast_hi_lo<<<dim3(32768), blk, 0, stream>>>(k, k_hi, k_lo, (long)32768 * 2048);
    gemm_bf16x3_bt<true, true><<<dim3(16, 256), blk, 0, stream>>>(
        k_hi, k_lo, wkThi, wkTlo, bk, nullptr, kp_hi, kp_lo, 32768, 2048, 2048);

    // Phase Q: qp in f32 (proven argmax q-side precision), into outcat region;
    // then invnorm + split into (qp_hi, qp_lo).
    gemm_f32<false, true, false><<<dim3(16, 13, 1), blk, 0, stream>>>(
        q, wq, bq, qpf, 1600, 2048, 2048, 2048, 2048, 2048, 0, 0, 0, 0, 0, 0);
    row_invnorm<<<dim3(800), blk, 0, stream>>>(qpf, iqn, NN_, (long)NQ_ * E_);
    split_cast_hi_lo<<<dim3(1600), blk, 0, stream>>>(qpf, qp_hi, qp_lo, (long)1600 * 2048);

    // Phase V: vp via bf16 MFMA, two M-chunks (scratch in S region; frees the
    // vp region that k_hi/k_lo occupied).
    transpose_cast<<<dim3(64, 64), blk, 0, stream>>>(wv, wT1, 2048, 2048);
    for (int c = 0; c < 2; ++c) {
        cast_f32_bf16<<<dim3(16384), blk, 0, stream>>>(
            v + (long)c * 16384 * 2048, v_bf16c, (long)16384 * 2048);
        gemm_bf16_bt<true><<<dim3(16, 128), blk, 0, stream>>>(
            v_bf16c, wT1, bv, vp + (long)c * 16384 * 2048, 16384, 2048, 2048);
    }

    // kp norms from hi/lo planes.
    row_invnorm_hl<<<dim3(32768), blk, 0, stream>>>(kp_hi, kp_lo, ikn);

    // Phase C: attn1 raw scores (bf16x3 MFMA) -> S region; memset outcat
    // (qpf scratch is dead now); fused gumbel argmax + LDS scatter.
    attn_scores_bf16x3<<<dim3(32, 1, 64), blk, 0, stream>>>(
        qp_hi, qp_lo, kp_hi, kp_lo, Sreg, 0);
    hipMemsetAsync(outcat, 0, 13107200, stream);
    gumbel_argmax_scatter_v3<<<dim3(4, 8, 8), blk, 0, stream>>>(
        Sreg, vp, iqn, ikn, tau, outcat);

    // Phase D: attn2 scores (bf16x3) -> softmax -> PV (f32, split-K x4 atomic)
    attn_scores_bf16x3<<<dim3(32, 1, 64), blk, 0, stream>>>(
        qp_hi, qp_lo, kp_hi, kp_lo, Sreg, NN_);
    softmax_rows<<<dim3(6400), blk, 0, stream>>>(Sreg);
    gemm_f32<false, false, true><<<dim3(2, 1, 256), blk, 0, stream>>>(
        Sreg, vp, nullptr, outcat + (long)NN_ * E_,
        100, 256, 1024, 4096, 2048, 2048,
        (long)H_ * NN_ * S_, (long)NN_ * S_,
        (long)S_ * E_, (long)CH_,
        (long)NQ_ * E_, (long)CH_);

    // Phase E: final projection via bf16 MFMA (S region reused for scratch)
    cast_f32_bf16<<<dim3(1600), blk, 0, stream>>>(outcat, out_bf16, (long)1600 * 2048);
    transpose_cast<<<dim3(64, 64), blk, 0, stream>>>(wo, wT2, 2048, 2048);
    gemm_bf16_bt<true><<<dim3(16, 13), blk, 0, stream>>>(
        out_bf16, wT2, bo, (float*)d_out, 1600, 2048, 2048);
}